// Round 5
// baseline (421.966 us; speedup 1.0000x reference)
//
#include <hip/hip_runtime.h>
#include <math.h>

// Shapes (fixed by the reference)
#define B_  16
#define R_  4096
#define C_  16
#define OC_ 32
#define IC_ 32
#define CO_ 512   // C_*OC_
#define NIDX (B_*CO_)       // 8192 output elements
#define NGRP 16             // fallback stage-A p-groups

// Persistent geometry: 512 blocks x 256 threads. __launch_bounds__(256,2)
// caps VGPR at 256 (R4 measured 128) -> 2 blocks/CU co-resident by
// construction on 256 CUs; no runtime occupancy guard (R4 showed those host
// queries silently fail under graph capture and divert the timed run).
#define NBF 512
#define CHF 8               // routes per block = R_/NBF

typedef unsigned int uint;
typedef unsigned short ushort;

typedef __attribute__((ext_vector_type(8))) short bf16x8;   // 8 bf16 = 4 VGPR
typedef __attribute__((ext_vector_type(4))) float f32x4;    // MFMA acc

__device__ __forceinline__ ushort f2bf(float f) {           // RNE float->bf16
  uint u = __float_as_uint(f);
  return (ushort)((u + 0x7FFFu + ((u >> 16) & 1u)) >> 16);
}
__device__ __forceinline__ float bf2f(ushort h) {
  return __uint_as_float(((uint)h) << 16);
}

// Grid barrier, fixed spin semantics (R3/R4 post-mortem):
//  - arrival: ONE release fetch_add per block (vmcnt drain + single L2 wb)
//  - spin:    RELAXED agent loads (LLC reads, NO per-iteration buffer_inv)
//  - exit:    ONE acquire load (single L1/L2 invalidate)
// __syncthreads() drains each wave's vmcnt before arrival (compiler emits
// s_waitcnt vmcnt(0) before s_barrier), so all block stores are in L2 before
// the release writeback.
__device__ __forceinline__ void gbar(uint* bar, uint target) {
  __syncthreads();
  if (threadIdx.x == 0) {
    __hip_atomic_fetch_add(bar, 1u, __ATOMIC_RELEASE, __HIP_MEMORY_SCOPE_AGENT);
    while (__hip_atomic_load(bar, __ATOMIC_RELAXED, __HIP_MEMORY_SCOPE_AGENT) < target) {
      __builtin_amdgcn_s_sleep(8);
    }
    (void)__hip_atomic_load(bar, __ATOMIC_ACQUIRE, __HIP_MEMORY_SCOPE_AGENT);
  }
  __syncthreads();
}

// ---- reduce + squash phase: block blk owns co = blk (16 b's) --------------
template<int ROUND>
__device__ __forceinline__ void reduce_phase(
    const float* __restrict__ s_part, const float* __restrict__ z_part,
    float* __restrict__ v_buf, float* __restrict__ out,
    float (&red)[16][17], float& zsh, int blk, int tid)
{
  {
    const int b = tid & 15, sl = tid >> 4;        // 16 p-slices x 16 b
    const float* basep = s_part + blk * 16 + b;
    float a0 = 0.f, a1 = 0.f, a2 = 0.f, a3 = 0.f;
#pragma unroll
    for (int p = sl; p < NBF; p += 64) {
      a0 += basep[(size_t)(p)      * NIDX];
      a1 += basep[(size_t)(p + 16) * NIDX];
      a2 += basep[(size_t)(p + 32) * NIDX];
      a3 += basep[(size_t)(p + 48) * NIDX];
    }
    red[sl][b] = (a0 + a1) + (a2 + a3);
  }
  if (ROUND > 0 && tid < 64) {                    // softmax denominator Z[c]
    const int c = blk >> 5;
    float zp = 0.f;
#pragma unroll
    for (int k = 0; k < NBF / 64; ++k) zp += z_part[(tid + 64 * k) * C_ + c];
#pragma unroll
    for (int off = 32; off >= 1; off >>= 1) zp += __shfl_xor(zp, off, 64);
    if (tid == 0) zsh = zp;
  }
  __syncthreads();
  if (tid < 16) {
    float acc = 0.f;
#pragma unroll
    for (int s8 = 0; s8 < 16; ++s8) acc += red[s8][tid];
    float Z  = (ROUND == 0) ? (float)R_ : zsh;
    float s  = acc / Z;
    float sq = s * s;
    float vv = sq * s / ((1.f + sq) * sqrtf(sq));  // exact reference formula
    if (ROUND == 2) out[tid * CO_ + blk] = vv;     // [b][c][o], co = blk
    else            v_buf[blk * 16 + tid] = vv;    // [co][b]
  }
  __syncthreads();
}

// ---- light phase: agreement + b-update + weighted sum; u_hat from HBM/LLC --
template<int ROUND>
__device__ __forceinline__ void light_phase(
    const ushort* __restrict__ uhat, f32x4 (&sacc)[8], float (*b_w)[4],
    const float* __restrict__ v_buf, float* __restrict__ s_part,
    float* __restrict__ z_part, int blk, int wid, int lane, int col, int krow,
    int r0)
{
  float4 vr[8];
#pragma unroll
  for (int j = 0; j < 8; ++j) {
    const int co = (wid * 8 + j) * 16 + col;
    vr[j] = *(const float4*)(v_buf + co * B_ + krow * 4);
  }
#pragma unroll
  for (int j = 0; j < 8; ++j) sacc[j] = (f32x4){0.f, 0.f, 0.f, 0.f};
  float zacc[4] = {0.f, 0.f, 0.f, 0.f};

#pragma unroll
  for (int rr = 0; rr < CHF; ++rr) {
    const int r = r0 + rr;
    uint2 q8[8];
#pragma unroll
    for (int j = 0; j < 8; ++j) {
      const int co = (wid * 8 + j) * 16 + col;
      q8[j] = *(const uint2*)(uhat + ((size_t)r * CO_ + co) * B_ + krow * 4);
    }
    float ap[4];
#pragma unroll
    for (int jj = 0; jj < 4; ++jj) {
      float s0 = 0.f;
#pragma unroll
      for (int jk = 0; jk < 2; ++jk) {
        const uint2  q  = q8[jj * 2 + jk];
        const float4 vv = vr[jj * 2 + jk];
        s0 = fmaf(__uint_as_float(q.x << 16),          vv.x, s0);
        s0 = fmaf(__uint_as_float(q.x & 0xFFFF0000u),  vv.y, s0);
        s0 = fmaf(__uint_as_float(q.y << 16),          vv.z, s0);
        s0 = fmaf(__uint_as_float(q.y & 0xFFFF0000u),  vv.w, s0);
      }
      ap[jj] = s0;
    }
    // 64-lane butterfly: sums over all 16 b (krow x reg) and 32 o (col x jk)
#pragma unroll
    for (int off = 1; off <= 32; off <<= 1) {
#pragma unroll
      for (int jj = 0; jj < 4; ++jj) ap[jj] += __shfl_xor(ap[jj], off, 64);
    }
    float wexp[4];
#pragma unroll
    for (int jj = 0; jj < 4; ++jj) {
      float bn = b_w[rr][jj] + ap[jj] * (1.f / 16.f);
      wexp[jj] = __expf(bn);
      zacc[jj] += wexp[jj];
      if (lane == 0) b_w[rr][jj] = bn;   // same-wave LDS: no barrier needed
    }
#pragma unroll
    for (int j = 0; j < 8; ++j) {
      const float w = wexp[j >> 1];
      const uint2 q = q8[j];
      sacc[j][0] = fmaf(w, __uint_as_float(q.x << 16),         sacc[j][0]);
      sacc[j][1] = fmaf(w, __uint_as_float(q.x & 0xFFFF0000u), sacc[j][1]);
      sacc[j][2] = fmaf(w, __uint_as_float(q.y << 16),         sacc[j][2]);
      sacc[j][3] = fmaf(w, __uint_as_float(q.y & 0xFFFF0000u), sacc[j][3]);
    }
  }
  float* sp = s_part + (size_t)blk * NIDX;
#pragma unroll
  for (int j = 0; j < 8; ++j) {
    const int co = (wid * 8 + j) * 16 + col;
    *(f32x4*)(sp + co * B_ + krow * 4) = sacc[j];
  }
  if (lane == 0) {
#pragma unroll
    for (int jj = 0; jj < 4; ++jj) z_part[blk * C_ + wid * 4 + jj] = zacc[jj];
  }
}

// ---------------------------------------------------------------------------
// Persistent fused kernel (u_hat staged in HBM). Frag maps (m89/m97-verified):
// A row=lane&15 (=b), k=(lane>>4)*8+idx; B col=lane&15 (=co off), k contig;
// C/D col=lane&15 (=co off), row b=(lane>>4)*4+reg.
// Numerics verified end-to-end in R3's timed run (absmax 0.001953, passed).
// ---------------------------------------------------------------------------
__global__ __launch_bounds__(256, 2)
void fused_caps(const float* __restrict__ x, const float* __restrict__ W,
                ushort* __restrict__ uhat, float* __restrict__ s_part,
                float* __restrict__ z_part, float* __restrict__ v_buf,
                float* __restrict__ out, uint* __restrict__ bar)
{
  const int tid  = threadIdx.x;
  const int wid  = tid >> 6;
  const int lane = tid & 63;
  const int col  = lane & 15;
  const int krow = lane >> 4;
  const int blk  = blockIdx.x;
  const int r0   = blk * CHF;

  __shared__ float b_lds[4][CHF][4];   // routing logits [wave][rr][cidx]
  __shared__ float red[16][17];
  __shared__ float zsh;

  if (lane < CHF * 4) b_lds[wid][lane >> 2][lane & 3] = 0.f;

  // ---- Phase 0: stream W once; u_hat -> HBM (bf16); uniform-sum partials --
  f32x4 sacc[8];
#pragma unroll
  for (int j = 0; j < 8; ++j) sacc[j] = (f32x4){0.f, 0.f, 0.f, 0.f};

#pragma unroll
  for (int rr = 0; rr < CHF; ++rr) {
    const int r = r0 + rr;
    const float* xp = x + ((size_t)col * R_ + r) * IC_ + krow * 8;
    float4 x0 = *(const float4*)xp;
    float4 x1 = *(const float4*)(xp + 4);
    bf16x8 af;
    af[0] = (short)f2bf(x0.x); af[1] = (short)f2bf(x0.y);
    af[2] = (short)f2bf(x0.z); af[3] = (short)f2bf(x0.w);
    af[4] = (short)f2bf(x1.x); af[5] = (short)f2bf(x1.y);
    af[6] = (short)f2bf(x1.z); af[7] = (short)f2bf(x1.w);

#pragma unroll
    for (int j = 0; j < 8; ++j) {
      const int co = (wid * 8 + j) * 16 + col;
      const float* wp = W + ((size_t)r * CO_ + co) * IC_ + krow * 8;
      float4 w0 = *(const float4*)(wp);
      float4 w1 = *(const float4*)(wp + 4);
      bf16x8 bf;
      bf[0] = (short)f2bf(w0.x); bf[1] = (short)f2bf(w0.y);
      bf[2] = (short)f2bf(w0.z); bf[3] = (short)f2bf(w0.w);
      bf[4] = (short)f2bf(w1.x); bf[5] = (short)f2bf(w1.y);
      bf[6] = (short)f2bf(w1.z); bf[7] = (short)f2bf(w1.w);

      f32x4 d = __builtin_amdgcn_mfma_f32_16x16x32_bf16(
          af, bf, (f32x4){0.f, 0.f, 0.f, 0.f}, 0, 0, 0);
      sacc[j] += d;

      union { ushort us[4]; uint2 q; } pk;
      pk.us[0] = f2bf(d[0]); pk.us[1] = f2bf(d[1]);
      pk.us[2] = f2bf(d[2]); pk.us[3] = f2bf(d[3]);
      *(uint2*)(uhat + ((size_t)r * CO_ + co) * B_ + krow * 4) = pk.q;
    }
  }
  {
    float* sp = s_part + (size_t)blk * NIDX;
#pragma unroll
    for (int j = 0; j < 8; ++j) {
      const int co = (wid * 8 + j) * 16 + col;
      *(f32x4*)(sp + co * B_ + krow * 4) = sacc[j];
    }
  }

  gbar(bar, NBF * 1);
  reduce_phase<0>(s_part, z_part, v_buf, out, red, zsh, blk, tid);
  gbar(bar, NBF * 2);
  light_phase<1>(uhat, sacc, b_lds[wid], v_buf, s_part, z_part,
                 blk, wid, lane, col, krow, r0);
  gbar(bar, NBF * 3);
  reduce_phase<1>(s_part, z_part, v_buf, out, red, zsh, blk, tid);
  gbar(bar, NBF * 4);
  light_phase<2>(uhat, sacc, b_lds[wid], v_buf, s_part, z_part,
                 blk, wid, lane, col, krow, r0);
  gbar(bar, NBF * 5);
  reduce_phase<2>(s_part, z_part, v_buf, out, red, zsh, blk, tid);
}

// ---------------------------------------------------------------------------
// FALLBACK path B (tiny ws only): heavy VALU path, two-stage reduce.
// ---------------------------------------------------------------------------
__global__ __launch_bounds__(256)
void reduce_stageA(const float* __restrict__ s_part, const float* __restrict__ z_part,
                   float* __restrict__ s_mid, float* __restrict__ z_mid, int ppg)
{
  const int idx = blockIdx.x * 256 + threadIdx.x;
  const int g   = blockIdx.y;
  const float* base = s_part + (size_t)g * ppg * NIDX + idx;
  float a0 = 0.f, a1 = 0.f, a2 = 0.f, a3 = 0.f;
  for (int p = 0; p < ppg; p += 4) {
    a0 += base[(size_t)(p + 0) * NIDX];
    a1 += base[(size_t)(p + 1) * NIDX];
    a2 += base[(size_t)(p + 2) * NIDX];
    a3 += base[(size_t)(p + 3) * NIDX];
  }
  s_mid[(size_t)g * NIDX + idx] = (a0 + a1) + (a2 + a3);

  if (blockIdx.x == 0 && threadIdx.x < C_) {
    float z0 = 0.f, z1 = 0.f, z2 = 0.f, z3 = 0.f;
    const float* zb = z_part + (size_t)g * ppg * C_ + threadIdx.x;
    for (int p = 0; p < ppg; p += 4) {
      z0 += zb[(p + 0) * C_];
      z1 += zb[(p + 1) * C_];
      z2 += zb[(p + 2) * C_];
      z3 += zb[(p + 3) * C_];
    }
    z_mid[g * C_ + threadIdx.x] = (z0 + z1) + (z2 + z3);
  }
}

template<int FINAL, int UNIFORM>
__global__ __launch_bounds__(256)
void reduce_squashB(const float* __restrict__ s_mid, const float* __restrict__ z_mid,
                    float* __restrict__ v_buf, float* __restrict__ out)
{
  const int pos = blockIdx.x * 256 + threadIdx.x;
  const int co = pos >> 4, b = pos & 15;
  float acc = 0.f;
#pragma unroll
  for (int g = 0; g < NGRP; ++g) acc += s_mid[(size_t)g * NIDX + pos];
  float Z;
  if (UNIFORM) {
    Z = (float)R_;
  } else {
    const int c = co >> 5;
    float zs = 0.f;
#pragma unroll
    for (int g = 0; g < NGRP; ++g) zs += z_mid[g * C_ + c];
    Z = zs;
  }
  float s  = acc / Z;
  float sq = s * s;
  float vv = sq * s / ((1.f + sq) * sqrtf(sq));
  if (FINAL) out[b * CO_ + co] = vv; else v_buf[pos] = vv;
}

template<int MODE>
__global__ __launch_bounds__(256)
void heavy_pass(const float* __restrict__ x, const float* __restrict__ W,
                const float* __restrict__ v, float* __restrict__ b_buf,
                float* __restrict__ s_part, float* __restrict__ z_part,
                int chunk)
{
  const int t  = threadIdx.x;
  const int co0 = t, co1 = t + 256;
  const int c0 = co0 >> 5, o0 = co0 & 31;
  const int c1 = co1 >> 5;
  const int r0 = blockIdx.x * chunk;

  float sacc0[B_], sacc1[B_];
#pragma unroll
  for (int b = 0; b < B_; ++b) { sacc0[b] = 0.f; sacc1[b] = 0.f; }
  float v0r[B_], v1r[B_];
  if (MODE == 1) {
#pragma unroll
    for (int b = 0; b < B_; ++b) { v0r[b] = v[co0*B_ + b]; v1r[b] = v[co1*B_ + b]; }
  }
  float zacc0 = 0.f, zacc1 = 0.f;

  for (int rr = 0; rr < chunk; ++rr) {
    const int r = r0 + rr;
    const float* Wr = W + (size_t)r * (CO_*IC_);
    const float* xr = x + (size_t)r * IC_;
    float u0[B_], u1[B_];
#pragma unroll
    for (int b = 0; b < B_; ++b) { u0[b] = 0.f; u1[b] = 0.f; }
#pragma unroll
    for (int ic = 0; ic < IC_; ic += 8) {
      float w0c[8], w1c[8];
#pragma unroll
      for (int i = 0; i < 8; i += 4) {
        *(float4*)&w0c[i] = *(const float4*)&Wr[co0*IC_ + ic + i];
        *(float4*)&w1c[i] = *(const float4*)&Wr[co1*IC_ + ic + i];
      }
#pragma unroll
      for (int b = 0; b < B_; ++b) {
        const float* xb = xr + (size_t)b * (R_*IC_) + ic;
#pragma unroll
        for (int i = 0; i < 8; ++i) {
          float xv = xb[i];
          u0[b] = fmaf(w0c[i], xv, u0[b]);
          u1[b] = fmaf(w1c[i], xv, u1[b]);
        }
      }
    }
    float wgt0 = 1.f, wgt1 = 1.f;
    if (MODE == 1) {
      float aa0 = 0.f, aa1 = 0.f;
#pragma unroll
      for (int b = 0; b < B_; ++b) { aa0 = fmaf(u0[b], v0r[b], aa0); aa1 = fmaf(u1[b], v1r[b], aa1); }
#pragma unroll
      for (int off = 16; off >= 1; off >>= 1) { aa0 += __shfl_xor(aa0, off, 32); aa1 += __shfl_xor(aa1, off, 32); }
      float bn0 = b_buf[r*C_ + c0] + aa0 * (1.f/16.f);
      float bn1 = b_buf[r*C_ + c1] + aa1 * (1.f/16.f);
      wgt0 = __expf(bn0); wgt1 = __expf(bn1);
      zacc0 += wgt0; zacc1 += wgt1;
      if (o0 == 0) { b_buf[r*C_ + c0] = bn0; b_buf[r*C_ + c1] = bn1; }
    }
#pragma unroll
    for (int b = 0; b < B_; ++b) { sacc0[b] = fmaf(wgt0, u0[b], sacc0[b]); sacc1[b] = fmaf(wgt1, u1[b], sacc1[b]); }
  }
  float* sp = s_part + (size_t)blockIdx.x * NIDX;
#pragma unroll
  for (int b = 0; b < B_; ++b) { sp[co0*B_ + b] = sacc0[b]; sp[co1*B_ + b] = sacc1[b]; }
  if (MODE == 1 && o0 == 0) { z_part[blockIdx.x*C_ + c0] = zacc0; z_part[blockIdx.x*C_ + c1] = zacc1; }
}

extern "C" void kernel_launch(void* const* d_in, const int* in_sizes, int n_in,
                              void* d_out, int out_size, void* d_ws, size_t ws_size,
                              hipStream_t stream)
{
  const float* x = (const float*)d_in[0];   // [B, R, IC] fp32
  const float* W = (const float*)d_in[1];   // [R, C, OC, IC] fp32 (268 MB)
  float* out = (float*)d_out;               // [B, C, OC, 1] fp32 = 8192 floats

  const size_t uhat_elems = (size_t)R_ * CO_ * B_;       // 33.5M bf16 = 67 MB

  // ---------------- Persistent fused path (no host queries) ----------------
  // ws: bar(256B) | uhat bf16 | s_part[NBF][NIDX] | z_part[NBF][C_] | v_buf
  {
    const size_t need = 256 + uhat_elems * 2 +
        ((size_t)NBF * NIDX + (size_t)NBF * C_ + NIDX) * sizeof(float);
    if (need <= ws_size) {
      uint*   bar    = (uint*)d_ws;
      ushort* uhat   = (ushort*)((char*)d_ws + 256);
      float*  s_part = (float*)(uhat + uhat_elems);
      float*  z_part = s_part + (size_t)NBF * NIDX;
      float*  v_buf  = z_part + (size_t)NBF * C_;

      (void)hipMemsetAsync(d_ws, 0, 256, stream);   // zero barrier counter
      fused_caps<<<NBF, 256, 0, stream>>>(x, W, uhat, s_part, z_part,
                                          v_buf, out, bar);
      return;
    }
  }

  // ---------------- Fallback: heavy path (tiny ws) ----------------
  const int nidx_blks = NIDX / 256;
  int NB = 512;
  while (NB > 64) {
    size_t need = ((size_t)NB * NIDX + (size_t)NB * C_ + (size_t)R_ * C_ + NIDX +
                   (size_t)NGRP * NIDX + NGRP * C_) * sizeof(float);
    if (need <= ws_size) break;
    NB >>= 1;
  }
  const int chunk = R_ / NB;
  const int ppg   = NB / NGRP;
  float* s_part = (float*)d_ws;
  float* z_part = s_part + (size_t)NB * NIDX;
  float* b_buf  = z_part + (size_t)NB * C_;
  float* v_buf  = b_buf  + (size_t)R_ * C_;
  float* s_mid  = v_buf  + NIDX;
  float* z_mid  = s_mid  + (size_t)NGRP * NIDX;

  (void)hipMemsetAsync(b_buf, 0, (size_t)R_ * C_ * sizeof(float), stream);
  heavy_pass<0><<<NB, 256, 0, stream>>>(x, W, nullptr, b_buf, s_part, z_part, chunk);
  reduce_stageA<<<dim3(nidx_blks, NGRP), 256, 0, stream>>>(s_part, z_part, s_mid, z_mid, ppg);
  reduce_squashB<0,1><<<nidx_blks, 256, 0, stream>>>(s_mid, z_mid, v_buf, nullptr);
  heavy_pass<1><<<NB, 256, 0, stream>>>(x, W, v_buf, b_buf, s_part, z_part, chunk);
  reduce_stageA<<<dim3(nidx_blks, NGRP), 256, 0, stream>>>(s_part, z_part, s_mid, z_mid, ppg);
  reduce_squashB<0,0><<<nidx_blks, 256, 0, stream>>>(s_mid, z_mid, v_buf, nullptr);
  heavy_pass<1><<<NB, 256, 0, stream>>>(x, W, v_buf, b_buf, s_part, z_part, chunk);
  reduce_stageA<<<dim3(nidx_blks, NGRP), 256, 0, stream>>>(s_part, z_part, s_mid, z_mid, ppg);
  reduce_squashB<1,0><<<nidx_blks, 256, 0, stream>>>(s_mid, z_mid, nullptr, out);
}

// Round 7
// 167.963 us; speedup vs baseline: 2.5123x; 2.5123x over previous
//
#include <hip/hip_runtime.h>
#include <math.h>

// Shapes (fixed by the reference)
#define B_  16
#define R_  4096
#define C_  16
#define OC_ 32
#define IC_ 32
#define CO_ 512   // C_*OC_
#define NIDX (B_*CO_)       // 8192 output elements
#define NGRP 16             // fallback stage-A p-groups

typedef unsigned int uint;
typedef unsigned short ushort;

typedef __attribute__((ext_vector_type(8))) short bf16x8;   // 8 bf16 = 4 VGPR
typedef __attribute__((ext_vector_type(4))) float f32x4;    // MFMA acc / nt loads
typedef __attribute__((ext_vector_type(2))) uint  u32x2;    // nt 8B store
typedef __attribute__((ext_vector_type(4))) uint  u32x4;    // nt 16B load

__device__ __forceinline__ ushort f2bf(float f) {           // RNE float->bf16
  uint u = __float_as_uint(f);
  return (ushort)((u + 0x7FFFu + ((u >> 16) & 1u)) >> 16);
}
__device__ __forceinline__ float bf2f(ushort h) {
  return __uint_as_float(((uint)h) << 16);
}

// ---------------------------------------------------------------------------
// Pass 0 (MFMA): stream W once (fp32, nt, convert in-reg); u_hat bf16 [r][co][b]
// (nt store) + uniform-sum partials s_part [blk][co][b]. CHUNK is a template
// parameter so the rr loop unrolls -> W loads for rr+1 issue under rr's
// convert/MFMA tail. nt builtins need ext_vector_type pointers (R6 lesson —
// HIP_vector_type float4/uint2 are rejected).
// Frag maps (m89/m97-verified): A row=lane&15 (=b), k=(lane>>4)*8+j contiguous;
// B col=lane&15 (=co), k contiguous; C/D col=lane&15 (=co), row b=(lane>>4)*4+reg.
// ---------------------------------------------------------------------------
template<int CHUNK>
__global__ __launch_bounds__(256)
void pass0_mfma(const float* __restrict__ x, const float* __restrict__ W,
                ushort* __restrict__ uhat, float* __restrict__ s_part,
                float* __restrict__ b_buf)
{
  const int wid  = threadIdx.x >> 6;      // 0..3
  const int lane = threadIdx.x & 63;
  const int col  = lane & 15;             // = b for A, = co-offset for B/C
  const int krow = lane >> 4;             // 0..3
  const int r0   = blockIdx.x * CHUNK;

  // zero routing logits for this block's routes (replaces memset dispatch)
  for (int i = threadIdx.x; i < CHUNK * C_; i += 256) b_buf[r0 * C_ + i] = 0.f;

  f32x4 sacc[8];
#pragma unroll
  for (int j = 0; j < 8; ++j) sacc[j] = (f32x4){0.f, 0.f, 0.f, 0.f};

#pragma unroll 2
  for (int rr = 0; rr < CHUNK; ++rr) {
    const int r = r0 + rr;
    // A-frag: x[b=col][r][krow*8 .. +8] fp32 -> bf16 in-reg (L2-hot, regular)
    const float* xp = x + ((size_t)col * R_ + r) * IC_ + krow * 8;
    float4 x0 = *(const float4*)xp;
    float4 x1 = *(const float4*)(xp + 4);
    bf16x8 af;
    af[0] = (short)f2bf(x0.x); af[1] = (short)f2bf(x0.y);
    af[2] = (short)f2bf(x0.z); af[3] = (short)f2bf(x0.w);
    af[4] = (short)f2bf(x1.x); af[5] = (short)f2bf(x1.y);
    af[6] = (short)f2bf(x1.z); af[7] = (short)f2bf(x1.w);

#pragma unroll
    for (int j = 0; j < 8; ++j) {
      const int co = (wid * 8 + j) * 16 + col;
      const f32x4* wp4 = (const f32x4*)(W + ((size_t)r * CO_ + co) * IC_ + krow * 8);
      f32x4 w0 = __builtin_nontemporal_load(wp4);       // W streamed once
      f32x4 w1 = __builtin_nontemporal_load(wp4 + 1);
      bf16x8 bf;
      bf[0] = (short)f2bf(w0.x); bf[1] = (short)f2bf(w0.y);
      bf[2] = (short)f2bf(w0.z); bf[3] = (short)f2bf(w0.w);
      bf[4] = (short)f2bf(w1.x); bf[5] = (short)f2bf(w1.y);
      bf[6] = (short)f2bf(w1.z); bf[7] = (short)f2bf(w1.w);

      f32x4 d = __builtin_amdgcn_mfma_f32_16x16x32_bf16(
          af, bf, (f32x4){0.f, 0.f, 0.f, 0.f}, 0, 0, 0);
      sacc[j] += d;

      // u_hat[r][co][b]: lane writes b = krow*4..+4 (8B, wave covers 512B), nt
      union { ushort us[4]; u32x2 q; } pk;
      pk.us[0] = f2bf(d[0]); pk.us[1] = f2bf(d[1]);
      pk.us[2] = f2bf(d[2]); pk.us[3] = f2bf(d[3]);
      __builtin_nontemporal_store(
          pk.q, (u32x2*)(uhat + ((size_t)r * CO_ + co) * B_ + krow * 4));
    }
  }

  // s_part layout [blk][co*B_ + b]: lane owns co, b = krow*4..+4 -> 16B store
  float* sp = s_part + (size_t)blockIdx.x * NIDX;
#pragma unroll
  for (int j = 0; j < 8; ++j) {
    const int co = (wid * 8 + j) * 16 + col;
    *(f32x4*)(sp + co * B_ + krow * 4) = sacc[j];
  }
}

// ---------------------------------------------------------------------------
// Light pass: fused agreement(it) + weighted-sum(it+1), streaming u_hat (bf16,
// nt loads — streamed once per pass). v and s_part in [co][b] layout.
// ---------------------------------------------------------------------------
__global__ __launch_bounds__(512)
void light_pass(const ushort* __restrict__ uhat, const float* __restrict__ v,
                float* __restrict__ b_buf, float* __restrict__ s_part,
                float* __restrict__ z_part, int chunk)
{
  const int t = threadIdx.x;                 // co = t
  const int c = t >> 5, o = t & 31;
  const int r0 = blockIdx.x * chunk;

  float vr[B_], sacc[B_];
#pragma unroll
  for (int k = 0; k < 4; ++k) *(float4*)&vr[4 * k] = *(const float4*)(v + t * B_ + 4 * k);
#pragma unroll
  for (int b = 0; b < B_; ++b) sacc[b] = 0.f;
  float zacc = 0.f;

#pragma unroll 2
  for (int rr = 0; rr < chunk; ++rr) {
    const int r = r0 + rr;
    const u32x4* up = (const u32x4*)(uhat + ((size_t)r * CO_ + t) * B_);
    union { ushort us[16]; u32x4 q[2]; } pk;
    pk.q[0] = __builtin_nontemporal_load(up);
    pk.q[1] = __builtin_nontemporal_load(up + 1);
    float u[B_]; float aa = 0.f;
#pragma unroll
    for (int b = 0; b < B_; ++b) { u[b] = bf2f(pk.us[b]); aa = fmaf(u[b], vr[b], aa); }
#pragma unroll
    for (int off = 16; off >= 1; off >>= 1) aa += __shfl_xor(aa, off, 32);
    float bn = b_buf[r * C_ + c] + aa * (1.f / 16.f);
    float w  = __expf(bn);
    zacc += w;
    if (o == 0) b_buf[r * C_ + c] = bn;
#pragma unroll
    for (int b = 0; b < B_; ++b) sacc[b] = fmaf(w, u[b], sacc[b]);
  }
  float* sp = s_part + (size_t)blockIdx.x * NIDX;
#pragma unroll
  for (int k = 0; k < 4; ++k) *(float4*)(sp + t * B_ + 4 * k) = *(float4*)&sacc[4 * k];
  if (o == 0) z_part[blockIdx.x * C_ + c] = zacc;
}

// ---------------------------------------------------------------------------
// Fused final reduce + normalize + squash.
// Grid 256 blocks x 256 threads: block handles 32 consecutive pos, 8 p-slices.
// ---------------------------------------------------------------------------
template<int FINAL, int UNIFORM>
__global__ __launch_bounds__(256)
void reduce_squash(const float* __restrict__ s_part, const float* __restrict__ z_part,
                   float* __restrict__ v_buf, float* __restrict__ out, int NB)
{
  __shared__ float red[8][32];
  __shared__ float zw[4];
  const int t   = threadIdx.x;
  const int sl  = t >> 5;                        // p-slice 0..7
  const int pos = blockIdx.x * 32 + (t & 31);

  const float* base = s_part + pos;
  float a0 = 0.f, a1 = 0.f, a2 = 0.f, a3 = 0.f;
  for (int p = sl; p < NB; p += 32) {            // NB multiple of 32
    a0 += base[(size_t)(p)      * NIDX];
    a1 += base[(size_t)(p + 8)  * NIDX];
    a2 += base[(size_t)(p + 16) * NIDX];
    a3 += base[(size_t)(p + 24) * NIDX];
  }
  red[sl][t & 31] = (a0 + a1) + (a2 + a3);

  if (!UNIFORM) {
    const int c = blockIdx.x >> 4;               // single c per 32-pos block
    float zp = 0.f;
    for (int p = t; p < NB; p += 256) zp += z_part[p * C_ + c];
#pragma unroll
    for (int off = 32; off >= 1; off >>= 1) zp += __shfl_down(zp, off, 64);
    if ((t & 63) == 0) zw[t >> 6] = zp;
  }
  __syncthreads();

  if (t < 32) {
    float acc = 0.f;
#pragma unroll
    for (int s8 = 0; s8 < 8; ++s8) acc += red[s8][t];
    float Z = UNIFORM ? (float)R_ : ((zw[0] + zw[1]) + (zw[2] + zw[3]));
    const int p2 = blockIdx.x * 32 + t;          // co*16 + b
    float s  = acc / Z;
    float sq = s * s;
    float vv = sq * s / ((1.f + sq) * sqrtf(sq));   // exact reference formula
    if (FINAL) out[(p2 & 15) * CO_ + (p2 >> 4)] = vv;
    else       v_buf[p2] = vv;
  }
}

// ---------------------------------------------------------------------------
// FALLBACK (tiny workspace only): 3x W reads, two-stage reduce. Unchanged.
// ---------------------------------------------------------------------------
__global__ __launch_bounds__(256)
void reduce_stageA(const float* __restrict__ s_part, const float* __restrict__ z_part,
                   float* __restrict__ s_mid, float* __restrict__ z_mid, int ppg)
{
  const int idx = blockIdx.x * 256 + threadIdx.x;
  const int g   = blockIdx.y;
  const float* base = s_part + (size_t)g * ppg * NIDX + idx;
  float a0 = 0.f, a1 = 0.f, a2 = 0.f, a3 = 0.f;
  for (int p = 0; p < ppg; p += 4) {
    a0 += base[(size_t)(p + 0) * NIDX];
    a1 += base[(size_t)(p + 1) * NIDX];
    a2 += base[(size_t)(p + 2) * NIDX];
    a3 += base[(size_t)(p + 3) * NIDX];
  }
  s_mid[(size_t)g * NIDX + idx] = (a0 + a1) + (a2 + a3);

  if (blockIdx.x == 0 && threadIdx.x < C_) {
    float z0 = 0.f, z1 = 0.f, z2 = 0.f, z3 = 0.f;
    const float* zb = z_part + (size_t)g * ppg * C_ + threadIdx.x;
    for (int p = 0; p < ppg; p += 4) {
      z0 += zb[(p + 0) * C_];
      z1 += zb[(p + 1) * C_];
      z2 += zb[(p + 2) * C_];
      z3 += zb[(p + 3) * C_];
    }
    z_mid[g * C_ + threadIdx.x] = (z0 + z1) + (z2 + z3);
  }
}

template<int FINAL, int UNIFORM>
__global__ __launch_bounds__(256)
void reduce_squashB(const float* __restrict__ s_mid, const float* __restrict__ z_mid,
                    float* __restrict__ v_buf, float* __restrict__ out)
{
  const int pos = blockIdx.x * 256 + threadIdx.x;
  const int co = pos >> 4, b = pos & 15;
  float acc = 0.f;
#pragma unroll
  for (int g = 0; g < NGRP; ++g) acc += s_mid[(size_t)g * NIDX + pos];
  float Z;
  if (UNIFORM) {
    Z = (float)R_;
  } else {
    const int c = co >> 5;
    float zs = 0.f;
#pragma unroll
    for (int g = 0; g < NGRP; ++g) zs += z_mid[g * C_ + c];
    Z = zs;
  }
  float s  = acc / Z;
  float sq = s * s;
  float vv = sq * s / ((1.f + sq) * sqrtf(sq));
  if (FINAL) out[b * CO_ + co] = vv; else v_buf[pos] = vv;
}

template<int MODE>
__global__ __launch_bounds__(256)
void heavy_pass(const float* __restrict__ x, const float* __restrict__ W,
                const float* __restrict__ v, float* __restrict__ b_buf,
                float* __restrict__ s_part, float* __restrict__ z_part,
                int chunk)
{
  const int t  = threadIdx.x;
  const int co0 = t, co1 = t + 256;
  const int c0 = co0 >> 5, o0 = co0 & 31;
  const int c1 = co1 >> 5;
  const int r0 = blockIdx.x * chunk;

  float sacc0[B_], sacc1[B_];
#pragma unroll
  for (int b = 0; b < B_; ++b) { sacc0[b] = 0.f; sacc1[b] = 0.f; }
  float v0r[B_], v1r[B_];
  if (MODE == 1) {
#pragma unroll
    for (int b = 0; b < B_; ++b) { v0r[b] = v[co0*B_ + b]; v1r[b] = v[co1*B_ + b]; }
  }
  float zacc0 = 0.f, zacc1 = 0.f;

  for (int rr = 0; rr < chunk; ++rr) {
    const int r = r0 + rr;
    const float* Wr = W + (size_t)r * (CO_*IC_);
    const float* xr = x + (size_t)r * IC_;
    float u0[B_], u1[B_];
#pragma unroll
    for (int b = 0; b < B_; ++b) { u0[b] = 0.f; u1[b] = 0.f; }
#pragma unroll
    for (int ic = 0; ic < IC_; ic += 8) {
      float w0c[8], w1c[8];
#pragma unroll
      for (int i = 0; i < 8; i += 4) {
        *(float4*)&w0c[i] = *(const float4*)&Wr[co0*IC_ + ic + i];
        *(float4*)&w1c[i] = *(const float4*)&Wr[co1*IC_ + ic + i];
      }
#pragma unroll
      for (int b = 0; b < B_; ++b) {
        const float* xb = xr + (size_t)b * (R_*IC_) + ic;
#pragma unroll
        for (int i = 0; i < 8; ++i) {
          float xv = xb[i];
          u0[b] = fmaf(w0c[i], xv, u0[b]);
          u1[b] = fmaf(w1c[i], xv, u1[b]);
        }
      }
    }
    float wgt0 = 1.f, wgt1 = 1.f;
    if (MODE == 1) {
      float aa0 = 0.f, aa1 = 0.f;
#pragma unroll
      for (int b = 0; b < B_; ++b) { aa0 = fmaf(u0[b], v0r[b], aa0); aa1 = fmaf(u1[b], v1r[b], aa1); }
#pragma unroll
      for (int off = 16; off >= 1; off >>= 1) { aa0 += __shfl_xor(aa0, off, 32); aa1 += __shfl_xor(aa1, off, 32); }
      float bn0 = b_buf[r*C_ + c0] + aa0 * (1.f/16.f);
      float bn1 = b_buf[r*C_ + c1] + aa1 * (1.f/16.f);
      wgt0 = __expf(bn0); wgt1 = __expf(bn1);
      zacc0 += wgt0; zacc1 += wgt1;
      if (o0 == 0) { b_buf[r*C_ + c0] = bn0; b_buf[r*C_ + c1] = bn1; }
    }
#pragma unroll
    for (int b = 0; b < B_; ++b) { sacc0[b] = fmaf(wgt0, u0[b], sacc0[b]); sacc1[b] = fmaf(wgt1, u1[b], sacc1[b]); }
  }
  float* sp = s_part + (size_t)blockIdx.x * NIDX;
#pragma unroll
  for (int b = 0; b < B_; ++b) { sp[co0*B_ + b] = sacc0[b]; sp[co1*B_ + b] = sacc1[b]; }
  if (MODE == 1 && o0 == 0) { z_part[blockIdx.x*C_ + c0] = zacc0; z_part[blockIdx.x*C_ + c1] = zacc1; }
}

extern "C" void kernel_launch(void* const* d_in, const int* in_sizes, int n_in,
                              void* d_out, int out_size, void* d_ws, size_t ws_size,
                              hipStream_t stream)
{
  const float* x = (const float*)d_in[0];   // [B, R, IC] fp32
  const float* W = (const float*)d_in[1];   // [R, C, OC, IC] fp32 (268 MB)
  float* out = (float*)d_out;               // [B, C, OC, 1] fp32 = 8192 floats

  const size_t uhat_elems = (size_t)R_ * CO_ * B_;       // 33.5M bf16 = 67 MB
  const int nidx_blks = NIDX / 256;                       // 32 (fallback)
  const int NBL_MAX = 512;                                // light-pass blocks

  // Fast path layout: uhat(bf16) | s_part[NB0][8192] | z_part | b_buf | v_buf
  int NB0 = 1024; bool fast = false;
  for (; NB0 >= 512; NB0 >>= 1) {
    size_t need = uhat_elems * 2 +
                  ((size_t)NB0 * NIDX + (size_t)NBL_MAX * C_ + (size_t)R_ * C_ + NIDX) * sizeof(float);
    if (need <= ws_size) { fast = true; break; }
  }

  if (fast) {
    const int NBL    = (NB0 < NBL_MAX) ? NB0 : NBL_MAX;
    const int chunkL = R_ / NBL;             // 8 at NBL=512
    ushort* uhat  = (ushort*)d_ws;
    float* s_part = (float*)(uhat + uhat_elems);
    float* z_part = s_part + (size_t)NB0 * NIDX;
    float* b_buf  = z_part + (size_t)NBL_MAX * C_;
    float* v_buf  = b_buf  + (size_t)R_ * C_;

    if (NB0 == 1024)
      pass0_mfma<4><<<1024, 256, 0, stream>>>(x, W, uhat, s_part, b_buf);
    else
      pass0_mfma<8><<<512, 256, 0, stream>>>(x, W, uhat, s_part, b_buf);
    reduce_squash<0,1><<<NIDX/32, 256, 0, stream>>>(s_part, z_part, v_buf, nullptr, NB0);

    light_pass<<<NBL, 512, 0, stream>>>(uhat, v_buf, b_buf, s_part, z_part, chunkL);
    reduce_squash<0,0><<<NIDX/32, 256, 0, stream>>>(s_part, z_part, v_buf, nullptr, NBL);

    light_pass<<<NBL, 512, 0, stream>>>(uhat, v_buf, b_buf, s_part, z_part, chunkL);
    reduce_squash<1,0><<<NIDX/32, 256, 0, stream>>>(s_part, z_part, nullptr, out, NBL);
    return;
  }

  // ---------------- Fallback: heavy path (tiny ws) ----------------
  int NB = 512;
  while (NB > 64) {
    size_t need = ((size_t)NB * NIDX + (size_t)NB * C_ + (size_t)R_ * C_ + NIDX +
                   (size_t)NGRP * NIDX + NGRP * C_) * sizeof(float);
    if (need <= ws_size) break;
    NB >>= 1;
  }
  const int chunk = R_ / NB;
  const int ppg   = NB / NGRP;
  float* s_part = (float*)d_ws;
  float* z_part = s_part + (size_t)NB * NIDX;
  float* b_buf  = z_part + (size_t)NB * C_;
  float* v_buf  = b_buf  + (size_t)R_ * C_;
  float* s_mid  = v_buf  + NIDX;
  float* z_mid  = s_mid  + (size_t)NGRP * NIDX;

  (void)hipMemsetAsync(b_buf, 0, (size_t)R_ * C_ * sizeof(float), stream);
  heavy_pass<0><<<NB, 256, 0, stream>>>(x, W, nullptr, b_buf, s_part, z_part, chunk);
  reduce_stageA<<<dim3(nidx_blks, NGRP), 256, 0, stream>>>(s_part, z_part, s_mid, z_mid, ppg);
  reduce_squashB<0,1><<<nidx_blks, 256, 0, stream>>>(s_mid, z_mid, v_buf, nullptr);
  heavy_pass<1><<<NB, 256, 0, stream>>>(x, W, v_buf, b_buf, s_part, z_part, chunk);
  reduce_stageA<<<dim3(nidx_blks, NGRP), 256, 0, stream>>>(s_part, z_part, s_mid, z_mid, ppg);
  reduce_squashB<0,0><<<nidx_blks, 256, 0, stream>>>(s_mid, z_mid, v_buf, nullptr);
  heavy_pass<1><<<NB, 256, 0, stream>>>(x, W, v_buf, b_buf, s_part, z_part, chunk);
  reduce_stageA<<<dim3(nidx_blks, NGRP), 256, 0, stream>>>(s_part, z_part, s_mid, z_mid, ppg);
  reduce_squashB<1,0><<<nidx_blks, 256, 0, stream>>>(s_mid, z_mid, nullptr, out);
}

// Round 8
// 146.237 us; speedup vs baseline: 2.8855x; 1.1486x over previous
//
#include <hip/hip_runtime.h>
#include <math.h>

// Shapes (fixed by the reference)
#define B_  16
#define R_  4096
#define C_  16
#define OC_ 32
#define IC_ 32
#define CO_ 512   // C_*OC_
#define NIDX (B_*CO_)       // 8192 output elements
#define NGRP 16             // fallback stage-A p-groups

typedef unsigned int uint;
typedef unsigned short ushort;

typedef __attribute__((ext_vector_type(8))) short bf16x8;   // 8 bf16 = 4 VGPR
typedef __attribute__((ext_vector_type(4))) float f32x4;    // MFMA acc / nt loads

__device__ __forceinline__ ushort f2bf(float f) {           // RNE float->bf16
  uint u = __float_as_uint(f);
  return (ushort)((u + 0x7FFFu + ((u >> 16) & 1u)) >> 16);
}
__device__ __forceinline__ float bf2f(ushort h) {
  return __uint_as_float(((uint)h) << 16);
}

// ---------------------------------------------------------------------------
// Pass 0 (MFMA): stream W once (fp32, NT — evict-first so the LLC retains
// uhat for the light passes; R7 showed nt on uhat itself costs ~+29 µs by
// killing that LLC reuse). u_hat bf16 [r][co][b] via NORMAL cached stores.
// CHUNK templated so rr loop unrolls (W loads for rr+1 under rr's tail).
// Frag maps (m89/m97-verified): A row=lane&15 (=b), k=(lane>>4)*8+j contiguous;
// B col=lane&15 (=co), k contiguous; C/D col=lane&15 (=co), row b=(lane>>4)*4+reg.
// ---------------------------------------------------------------------------
template<int CHUNK>
__global__ __launch_bounds__(256)
void pass0_mfma(const float* __restrict__ x, const float* __restrict__ W,
                ushort* __restrict__ uhat, float* __restrict__ s_part,
                float* __restrict__ b_buf)
{
  const int wid  = threadIdx.x >> 6;      // 0..3
  const int lane = threadIdx.x & 63;
  const int col  = lane & 15;             // = b for A, = co-offset for B/C
  const int krow = lane >> 4;             // 0..3
  const int r0   = blockIdx.x * CHUNK;

  // zero routing logits for this block's routes (replaces memset dispatch)
  for (int i = threadIdx.x; i < CHUNK * C_; i += 256) b_buf[r0 * C_ + i] = 0.f;

  f32x4 sacc[8];
#pragma unroll
  for (int j = 0; j < 8; ++j) sacc[j] = (f32x4){0.f, 0.f, 0.f, 0.f};

#pragma unroll 2
  for (int rr = 0; rr < CHUNK; ++rr) {
    const int r = r0 + rr;
    // A-frag: x[b=col][r][krow*8 .. +8] fp32 -> bf16 in-reg (L2-hot, regular)
    const float* xp = x + ((size_t)col * R_ + r) * IC_ + krow * 8;
    float4 x0 = *(const float4*)xp;
    float4 x1 = *(const float4*)(xp + 4);
    bf16x8 af;
    af[0] = (short)f2bf(x0.x); af[1] = (short)f2bf(x0.y);
    af[2] = (short)f2bf(x0.z); af[3] = (short)f2bf(x0.w);
    af[4] = (short)f2bf(x1.x); af[5] = (short)f2bf(x1.y);
    af[6] = (short)f2bf(x1.z); af[7] = (short)f2bf(x1.w);

#pragma unroll
    for (int j = 0; j < 8; ++j) {
      const int co = (wid * 8 + j) * 16 + col;
      const f32x4* wp4 = (const f32x4*)(W + ((size_t)r * CO_ + co) * IC_ + krow * 8);
      f32x4 w0 = __builtin_nontemporal_load(wp4);       // W streamed once (NT)
      f32x4 w1 = __builtin_nontemporal_load(wp4 + 1);
      bf16x8 bf;
      bf[0] = (short)f2bf(w0.x); bf[1] = (short)f2bf(w0.y);
      bf[2] = (short)f2bf(w0.z); bf[3] = (short)f2bf(w0.w);
      bf[4] = (short)f2bf(w1.x); bf[5] = (short)f2bf(w1.y);
      bf[6] = (short)f2bf(w1.z); bf[7] = (short)f2bf(w1.w);

      f32x4 d = __builtin_amdgcn_mfma_f32_16x16x32_bf16(
          af, bf, (f32x4){0.f, 0.f, 0.f, 0.f}, 0, 0, 0);
      sacc[j] += d;

      // u_hat[r][co][b]: lane writes b = krow*4..+4 (8B) — NORMAL store,
      // stays LLC-resident for the light passes.
      union { ushort us[4]; uint2 q; } pk;
      pk.us[0] = f2bf(d[0]); pk.us[1] = f2bf(d[1]);
      pk.us[2] = f2bf(d[2]); pk.us[3] = f2bf(d[3]);
      *(uint2*)(uhat + ((size_t)r * CO_ + co) * B_ + krow * 4) = pk.q;
    }
  }

  // s_part layout [blk][co*B_ + b]: lane owns co, b = krow*4..+4 -> 16B store
  float* sp = s_part + (size_t)blockIdx.x * NIDX;
#pragma unroll
  for (int j = 0; j < 8; ++j) {
    const int co = (wid * 8 + j) * 16 + col;
    *(f32x4*)(sp + co * B_ + krow * 4) = sacc[j];
  }
}

// ---------------------------------------------------------------------------
// Light pass: fused agreement(it) + weighted-sum(it+1), streaming u_hat (bf16,
// NORMAL cached loads — uhat is LLC-resident and read twice). [co][b] layouts.
// ---------------------------------------------------------------------------
__global__ __launch_bounds__(512)
void light_pass(const ushort* __restrict__ uhat, const float* __restrict__ v,
                float* __restrict__ b_buf, float* __restrict__ s_part,
                float* __restrict__ z_part, int chunk)
{
  const int t = threadIdx.x;                 // co = t
  const int c = t >> 5, o = t & 31;
  const int r0 = blockIdx.x * chunk;

  float vr[B_], sacc[B_];
#pragma unroll
  for (int k = 0; k < 4; ++k) *(float4*)&vr[4 * k] = *(const float4*)(v + t * B_ + 4 * k);
#pragma unroll
  for (int b = 0; b < B_; ++b) sacc[b] = 0.f;
  float zacc = 0.f;

#pragma unroll 2
  for (int rr = 0; rr < chunk; ++rr) {
    const int r = r0 + rr;
    const uint4* up = (const uint4*)(uhat + ((size_t)r * CO_ + t) * B_);
    union { ushort us[16]; uint4 q[2]; } pk;
    pk.q[0] = up[0]; pk.q[1] = up[1];
    float u[B_]; float aa = 0.f;
#pragma unroll
    for (int b = 0; b < B_; ++b) { u[b] = bf2f(pk.us[b]); aa = fmaf(u[b], vr[b], aa); }
#pragma unroll
    for (int off = 16; off >= 1; off >>= 1) aa += __shfl_xor(aa, off, 32);
    float bn = b_buf[r * C_ + c] + aa * (1.f / 16.f);
    float w  = __expf(bn);
    zacc += w;
    if (o == 0) b_buf[r * C_ + c] = bn;
#pragma unroll
    for (int b = 0; b < B_; ++b) sacc[b] = fmaf(w, u[b], sacc[b]);
  }
  float* sp = s_part + (size_t)blockIdx.x * NIDX;
#pragma unroll
  for (int k = 0; k < 4; ++k) *(float4*)(sp + t * B_ + 4 * k) = *(float4*)&sacc[4 * k];
  if (o == 0) z_part[blockIdx.x * C_ + c] = zacc;
}

// ---------------------------------------------------------------------------
// Fused final reduce + normalize + squash.
// Grid 256 blocks x 256 threads: block handles 32 consecutive pos, 8 p-slices.
// ---------------------------------------------------------------------------
template<int FINAL, int UNIFORM>
__global__ __launch_bounds__(256)
void reduce_squash(const float* __restrict__ s_part, const float* __restrict__ z_part,
                   float* __restrict__ v_buf, float* __restrict__ out, int NB)
{
  __shared__ float red[8][32];
  __shared__ float zw[4];
  const int t   = threadIdx.x;
  const int sl  = t >> 5;                        // p-slice 0..7
  const int pos = blockIdx.x * 32 + (t & 31);

  const float* base = s_part + pos;
  float a0 = 0.f, a1 = 0.f, a2 = 0.f, a3 = 0.f;
  for (int p = sl; p < NB; p += 32) {            // NB multiple of 32
    a0 += base[(size_t)(p)      * NIDX];
    a1 += base[(size_t)(p + 8)  * NIDX];
    a2 += base[(size_t)(p + 16) * NIDX];
    a3 += base[(size_t)(p + 24) * NIDX];
  }
  red[sl][t & 31] = (a0 + a1) + (a2 + a3);

  if (!UNIFORM) {
    const int c = blockIdx.x >> 4;               // single c per 32-pos block
    float zp = 0.f;
    for (int p = t; p < NB; p += 256) zp += z_part[p * C_ + c];
#pragma unroll
    for (int off = 32; off >= 1; off >>= 1) zp += __shfl_down(zp, off, 64);
    if ((t & 63) == 0) zw[t >> 6] = zp;
  }
  __syncthreads();

  if (t < 32) {
    float acc = 0.f;
#pragma unroll
    for (int s8 = 0; s8 < 8; ++s8) acc += red[s8][t];
    float Z = UNIFORM ? (float)R_ : ((zw[0] + zw[1]) + (zw[2] + zw[3]));
    const int p2 = blockIdx.x * 32 + t;          // co*16 + b
    float s  = acc / Z;
    float sq = s * s;
    float vv = sq * s / ((1.f + sq) * sqrtf(sq));   // exact reference formula
    if (FINAL) out[(p2 & 15) * CO_ + (p2 >> 4)] = vv;
    else       v_buf[p2] = vv;
  }
}

// ---------------------------------------------------------------------------
// FALLBACK (tiny workspace only): 3x W reads, two-stage reduce. Unchanged.
// ---------------------------------------------------------------------------
__global__ __launch_bounds__(256)
void reduce_stageA(const float* __restrict__ s_part, const float* __restrict__ z_part,
                   float* __restrict__ s_mid, float* __restrict__ z_mid, int ppg)
{
  const int idx = blockIdx.x * 256 + threadIdx.x;
  const int g   = blockIdx.y;
  const float* base = s_part + (size_t)g * ppg * NIDX + idx;
  float a0 = 0.f, a1 = 0.f, a2 = 0.f, a3 = 0.f;
  for (int p = 0; p < ppg; p += 4) {
    a0 += base[(size_t)(p + 0) * NIDX];
    a1 += base[(size_t)(p + 1) * NIDX];
    a2 += base[(size_t)(p + 2) * NIDX];
    a3 += base[(size_t)(p + 3) * NIDX];
  }
  s_mid[(size_t)g * NIDX + idx] = (a0 + a1) + (a2 + a3);

  if (blockIdx.x == 0 && threadIdx.x < C_) {
    float z0 = 0.f, z1 = 0.f, z2 = 0.f, z3 = 0.f;
    const float* zb = z_part + (size_t)g * ppg * C_ + threadIdx.x;
    for (int p = 0; p < ppg; p += 4) {
      z0 += zb[(p + 0) * C_];
      z1 += zb[(p + 1) * C_];
      z2 += zb[(p + 2) * C_];
      z3 += zb[(p + 3) * C_];
    }
    z_mid[g * C_ + threadIdx.x] = (z0 + z1) + (z2 + z3);
  }
}

template<int FINAL, int UNIFORM>
__global__ __launch_bounds__(256)
void reduce_squashB(const float* __restrict__ s_mid, const float* __restrict__ z_mid,
                    float* __restrict__ v_buf, float* __restrict__ out)
{
  const int pos = blockIdx.x * 256 + threadIdx.x;
  const int co = pos >> 4, b = pos & 15;
  float acc = 0.f;
#pragma unroll
  for (int g = 0; g < NGRP; ++g) acc += s_mid[(size_t)g * NIDX + pos];
  float Z;
  if (UNIFORM) {
    Z = (float)R_;
  } else {
    const int c = co >> 5;
    float zs = 0.f;
#pragma unroll
    for (int g = 0; g < NGRP; ++g) zs += z_mid[g * C_ + c];
    Z = zs;
  }
  float s  = acc / Z;
  float sq = s * s;
  float vv = sq * s / ((1.f + sq) * sqrtf(sq));
  if (FINAL) out[b * CO_ + co] = vv; else v_buf[pos] = vv;
}

template<int MODE>
__global__ __launch_bounds__(256)
void heavy_pass(const float* __restrict__ x, const float* __restrict__ W,
                const float* __restrict__ v, float* __restrict__ b_buf,
                float* __restrict__ s_part, float* __restrict__ z_part,
                int chunk)
{
  const int t  = threadIdx.x;
  const int co0 = t, co1 = t + 256;
  const int c0 = co0 >> 5, o0 = co0 & 31;
  const int c1 = co1 >> 5;
  const int r0 = blockIdx.x * chunk;

  float sacc0[B_], sacc1[B_];
#pragma unroll
  for (int b = 0; b < B_; ++b) { sacc0[b] = 0.f; sacc1[b] = 0.f; }
  float v0r[B_], v1r[B_];
  if (MODE == 1) {
#pragma unroll
    for (int b = 0; b < B_; ++b) { v0r[b] = v[co0*B_ + b]; v1r[b] = v[co1*B_ + b]; }
  }
  float zacc0 = 0.f, zacc1 = 0.f;

  for (int rr = 0; rr < chunk; ++rr) {
    const int r = r0 + rr;
    const float* Wr = W + (size_t)r * (CO_*IC_);
    const float* xr = x + (size_t)r * IC_;
    float u0[B_], u1[B_];
#pragma unroll
    for (int b = 0; b < B_; ++b) { u0[b] = 0.f; u1[b] = 0.f; }
#pragma unroll
    for (int ic = 0; ic < IC_; ic += 8) {
      float w0c[8], w1c[8];
#pragma unroll
      for (int i = 0; i < 8; i += 4) {
        *(float4*)&w0c[i] = *(const float4*)&Wr[co0*IC_ + ic + i];
        *(float4*)&w1c[i] = *(const float4*)&Wr[co1*IC_ + ic + i];
      }
#pragma unroll
      for (int b = 0; b < B_; ++b) {
        const float* xb = xr + (size_t)b * (R_*IC_) + ic;
#pragma unroll
        for (int i = 0; i < 8; ++i) {
          float xv = xb[i];
          u0[b] = fmaf(w0c[i], xv, u0[b]);
          u1[b] = fmaf(w1c[i], xv, u1[b]);
        }
      }
    }
    float wgt0 = 1.f, wgt1 = 1.f;
    if (MODE == 1) {
      float aa0 = 0.f, aa1 = 0.f;
#pragma unroll
      for (int b = 0; b < B_; ++b) { aa0 = fmaf(u0[b], v0r[b], aa0); aa1 = fmaf(u1[b], v1r[b], aa1); }
#pragma unroll
      for (int off = 16; off >= 1; off >>= 1) { aa0 += __shfl_xor(aa0, off, 32); aa1 += __shfl_xor(aa1, off, 32); }
      float bn0 = b_buf[r*C_ + c0] + aa0 * (1.f/16.f);
      float bn1 = b_buf[r*C_ + c1] + aa1 * (1.f/16.f);
      wgt0 = __expf(bn0); wgt1 = __expf(bn1);
      zacc0 += wgt0; zacc1 += wgt1;
      if (o0 == 0) { b_buf[r*C_ + c0] = bn0; b_buf[r*C_ + c1] = bn1; }
    }
#pragma unroll
    for (int b = 0; b < B_; ++b) { sacc0[b] = fmaf(wgt0, u0[b], sacc0[b]); sacc1[b] = fmaf(wgt1, u1[b], sacc1[b]); }
  }
  float* sp = s_part + (size_t)blockIdx.x * NIDX;
#pragma unroll
  for (int b = 0; b < B_; ++b) { sp[co0*B_ + b] = sacc0[b]; sp[co1*B_ + b] = sacc1[b]; }
  if (MODE == 1 && o0 == 0) { z_part[blockIdx.x*C_ + c0] = zacc0; z_part[blockIdx.x*C_ + c1] = zacc1; }
}

extern "C" void kernel_launch(void* const* d_in, const int* in_sizes, int n_in,
                              void* d_out, int out_size, void* d_ws, size_t ws_size,
                              hipStream_t stream)
{
  const float* x = (const float*)d_in[0];   // [B, R, IC] fp32
  const float* W = (const float*)d_in[1];   // [R, C, OC, IC] fp32 (268 MB)
  float* out = (float*)d_out;               // [B, C, OC, 1] fp32 = 8192 floats

  const size_t uhat_elems = (size_t)R_ * CO_ * B_;       // 33.5M bf16 = 67 MB
  const int nidx_blks = NIDX / 256;                       // 32 (fallback)
  const int NBL_MAX = 512;                                // light-pass blocks

  // Fast path layout: uhat(bf16) | s_part[NB0][8192] | z_part | b_buf | v_buf
  int NB0 = 1024; bool fast = false;
  for (; NB0 >= 512; NB0 >>= 1) {
    size_t need = uhat_elems * 2 +
                  ((size_t)NB0 * NIDX + (size_t)NBL_MAX * C_ + (size_t)R_ * C_ + NIDX) * sizeof(float);
    if (need <= ws_size) { fast = true; break; }
  }

  if (fast) {
    const int NBL    = (NB0 < NBL_MAX) ? NB0 : NBL_MAX;
    const int chunkL = R_ / NBL;             // 8 at NBL=512
    ushort* uhat  = (ushort*)d_ws;
    float* s_part = (float*)(uhat + uhat_elems);
    float* z_part = s_part + (size_t)NB0 * NIDX;
    float* b_buf  = z_part + (size_t)NBL_MAX * C_;
    float* v_buf  = b_buf  + (size_t)R_ * C_;

    if (NB0 == 1024)
      pass0_mfma<4><<<1024, 256, 0, stream>>>(x, W, uhat, s_part, b_buf);
    else
      pass0_mfma<8><<<512, 256, 0, stream>>>(x, W, uhat, s_part, b_buf);
    reduce_squash<0,1><<<NIDX/32, 256, 0, stream>>>(s_part, z_part, v_buf, nullptr, NB0);

    light_pass<<<NBL, 512, 0, stream>>>(uhat, v_buf, b_buf, s_part, z_part, chunkL);
    reduce_squash<0,0><<<NIDX/32, 256, 0, stream>>>(s_part, z_part, v_buf, nullptr, NBL);

    light_pass<<<NBL, 512, 0, stream>>>(uhat, v_buf, b_buf, s_part, z_part, chunkL);
    reduce_squash<1,0><<<NIDX/32, 256, 0, stream>>>(s_part, z_part, nullptr, out, NBL);
    return;
  }

  // ---------------- Fallback: heavy path (tiny ws) ----------------
  int NB = 512;
  while (NB > 64) {
    size_t need = ((size_t)NB * NIDX + (size_t)NB * C_ + (size_t)R_ * C_ + NIDX +
                   (size_t)NGRP * NIDX + NGRP * C_) * sizeof(float);
    if (need <= ws_size) break;
    NB >>= 1;
  }
  const int chunk = R_ / NB;
  const int ppg   = NB / NGRP;
  float* s_part = (float*)d_ws;
  float* z_part = s_part + (size_t)NB * NIDX;
  float* b_buf  = z_part + (size_t)NB * C_;
  float* v_buf  = b_buf  + (size_t)R_ * C_;
  float* s_mid  = v_buf  + NIDX;
  float* z_mid  = s_mid  + (size_t)NGRP * NIDX;

  (void)hipMemsetAsync(b_buf, 0, (size_t)R_ * C_ * sizeof(float), stream);
  heavy_pass<0><<<NB, 256, 0, stream>>>(x, W, nullptr, b_buf, s_part, z_part, chunk);
  reduce_stageA<<<dim3(nidx_blks, NGRP), 256, 0, stream>>>(s_part, z_part, s_mid, z_mid, ppg);
  reduce_squashB<0,1><<<nidx_blks, 256, 0, stream>>>(s_mid, z_mid, v_buf, nullptr);
  heavy_pass<1><<<NB, 256, 0, stream>>>(x, W, v_buf, b_buf, s_part, z_part, chunk);
  reduce_stageA<<<dim3(nidx_blks, NGRP), 256, 0, stream>>>(s_part, z_part, s_mid, z_mid, ppg);
  reduce_squashB<0,0><<<nidx_blks, 256, 0, stream>>>(s_mid, z_mid, v_buf, nullptr);
  heavy_pass<1><<<NB, 256, 0, stream>>>(x, W, v_buf, b_buf, s_part, z_part, chunk);
  reduce_stageA<<<dim3(nidx_blks, NGRP), 256, 0, stream>>>(s_part, z_part, s_mid, z_mid, ppg);
  reduce_squashB<1,0><<<nidx_blks, 256, 0, stream>>>(s_mid, z_mid, nullptr, out);
}

// Round 9
// 138.670 us; speedup vs baseline: 3.0430x; 1.0546x over previous
//
#include <hip/hip_runtime.h>
#include <math.h>

// Shapes (fixed by the reference)
#define B_  16
#define R_  4096
#define C_  16
#define OC_ 32
#define IC_ 32
#define CO_ 512   // C_*OC_
#define NIDX (B_*CO_)       // 8192 output elements
#define NGRP 16             // fallback stage-A p-groups

typedef unsigned int uint;
typedef unsigned short ushort;

typedef __attribute__((ext_vector_type(8))) short bf16x8;   // 8 bf16 = 4 VGPR
typedef __attribute__((ext_vector_type(4))) float f32x4;    // MFMA acc

__device__ __forceinline__ ushort f2bf(float f) {           // RNE float->bf16
  uint u = __float_as_uint(f);
  return (ushort)((u + 0x7FFFu + ((u >> 16) & 1u)) >> 16);
}
__device__ __forceinline__ float bf2f(ushort h) {
  return __uint_as_float(((uint)h) << 16);
}

// ---------------------------------------------------------------------------
// Pass 0 (MFMA): read W once (fp32, plain cached loads — R7/R8 proved nt hints
// regress on gfx950), u_hat bf16 [r][co][b] + uniform-sum partials
// s_part [blk][co][b]. Byte-identical body to the verified 139.2 µs kernel;
// only the host-side NB0 changed (1024 -> 512) to halve s_part traffic.
// Frag maps (m89/m97-verified): A row=lane&15 (=b), k=(lane>>4)*8+j contiguous;
// B col=lane&15 (=co), k contiguous; C/D col=lane&15 (=co), row b=(lane>>4)*4+reg.
// ---------------------------------------------------------------------------
__global__ __launch_bounds__(256)
void pass0_mfma(const float* __restrict__ x, const float* __restrict__ W,
                ushort* __restrict__ uhat, float* __restrict__ s_part,
                float* __restrict__ b_buf, int chunk)
{
  const int wid  = threadIdx.x >> 6;      // 0..3
  const int lane = threadIdx.x & 63;
  const int col  = lane & 15;             // = b for A, = co-offset for B/C
  const int krow = lane >> 4;             // 0..3
  const int r0   = blockIdx.x * chunk;

  // zero routing logits for this block's routes (replaces memset dispatch)
  for (int i = threadIdx.x; i < chunk * C_; i += 256) b_buf[r0 * C_ + i] = 0.f;

  f32x4 sacc[8];
#pragma unroll
  for (int j = 0; j < 8; ++j) sacc[j] = (f32x4){0.f, 0.f, 0.f, 0.f};

  for (int rr = 0; rr < chunk; ++rr) {
    const int r = r0 + rr;
    // A-frag: x[b=col][r][krow*8 .. +8] fp32 -> bf16 in-reg (L2-hot)
    const float* xp = x + ((size_t)col * R_ + r) * IC_ + krow * 8;
    float4 x0 = *(const float4*)xp;
    float4 x1 = *(const float4*)(xp + 4);
    bf16x8 af;
    af[0] = (short)f2bf(x0.x); af[1] = (short)f2bf(x0.y);
    af[2] = (short)f2bf(x0.z); af[3] = (short)f2bf(x0.w);
    af[4] = (short)f2bf(x1.x); af[5] = (short)f2bf(x1.y);
    af[6] = (short)f2bf(x1.z); af[7] = (short)f2bf(x1.w);

#pragma unroll
    for (int j = 0; j < 8; ++j) {
      const int co = (wid * 8 + j) * 16 + col;
      const float* wp = W + ((size_t)r * CO_ + co) * IC_ + krow * 8;
      float4 w0 = *(const float4*)(wp);
      float4 w1 = *(const float4*)(wp + 4);
      bf16x8 bf;
      bf[0] = (short)f2bf(w0.x); bf[1] = (short)f2bf(w0.y);
      bf[2] = (short)f2bf(w0.z); bf[3] = (short)f2bf(w0.w);
      bf[4] = (short)f2bf(w1.x); bf[5] = (short)f2bf(w1.y);
      bf[6] = (short)f2bf(w1.z); bf[7] = (short)f2bf(w1.w);

      f32x4 d = __builtin_amdgcn_mfma_f32_16x16x32_bf16(
          af, bf, (f32x4){0.f, 0.f, 0.f, 0.f}, 0, 0, 0);
      sacc[j] += d;

      // u_hat[r][co][b]: lane writes b = krow*4 .. +4 (8B, coalesced), cached
      union { ushort us[4]; uint2 q; } pk;
      pk.us[0] = f2bf(d[0]); pk.us[1] = f2bf(d[1]);
      pk.us[2] = f2bf(d[2]); pk.us[3] = f2bf(d[3]);
      *(uint2*)(uhat + ((size_t)r * CO_ + co) * B_ + krow * 4) = pk.q;
    }
  }

  // s_part layout [blk][co*B_ + b]: lane owns co, b = krow*4..+4 -> 16B store
  float* sp = s_part + (size_t)blockIdx.x * NIDX;
#pragma unroll
  for (int j = 0; j < 8; ++j) {
    const int co = (wid * 8 + j) * 16 + col;
    *(f32x4*)(sp + co * B_ + krow * 4) = sacc[j];
  }
}

// ---------------------------------------------------------------------------
// Light pass: fused agreement(it) + weighted-sum(it+1), streaming u_hat (bf16,
// plain cached loads). v and s_part in [co][b] layout.
// ---------------------------------------------------------------------------
__global__ __launch_bounds__(512)
void light_pass(const ushort* __restrict__ uhat, const float* __restrict__ v,
                float* __restrict__ b_buf, float* __restrict__ s_part,
                float* __restrict__ z_part, int chunk)
{
  const int t = threadIdx.x;                 // co = t
  const int c = t >> 5, o = t & 31;
  const int r0 = blockIdx.x * chunk;

  float vr[B_], sacc[B_];
#pragma unroll
  for (int k = 0; k < 4; ++k) *(float4*)&vr[4 * k] = *(const float4*)(v + t * B_ + 4 * k);
#pragma unroll
  for (int b = 0; b < B_; ++b) sacc[b] = 0.f;
  float zacc = 0.f;

#pragma unroll 2
  for (int rr = 0; rr < chunk; ++rr) {
    const int r = r0 + rr;
    const uint4* up = (const uint4*)(uhat + ((size_t)r * CO_ + t) * B_);
    union { ushort us[16]; uint4 q[2]; } pk;
    pk.q[0] = up[0]; pk.q[1] = up[1];
    float u[B_]; float aa = 0.f;
#pragma unroll
    for (int b = 0; b < B_; ++b) { u[b] = bf2f(pk.us[b]); aa = fmaf(u[b], vr[b], aa); }
#pragma unroll
    for (int off = 16; off >= 1; off >>= 1) aa += __shfl_xor(aa, off, 32);
    float bn = b_buf[r * C_ + c] + aa * (1.f / 16.f);
    float w  = __expf(bn);
    zacc += w;
    if (o == 0) b_buf[r * C_ + c] = bn;
#pragma unroll
    for (int b = 0; b < B_; ++b) sacc[b] = fmaf(w, u[b], sacc[b]);
  }
  float* sp = s_part + (size_t)blockIdx.x * NIDX;
#pragma unroll
  for (int k = 0; k < 4; ++k) *(float4*)(sp + t * B_ + 4 * k) = *(float4*)&sacc[4 * k];
  if (o == 0) z_part[blockIdx.x * C_ + c] = zacc;
}

// ---------------------------------------------------------------------------
// Fused final reduce + normalize + squash.
// Grid 256 blocks x 256 threads: block handles 32 consecutive pos, 8 p-slices.
// ---------------------------------------------------------------------------
template<int FINAL, int UNIFORM>
__global__ __launch_bounds__(256)
void reduce_squash(const float* __restrict__ s_part, const float* __restrict__ z_part,
                   float* __restrict__ v_buf, float* __restrict__ out, int NB)
{
  __shared__ float red[8][32];
  __shared__ float zw[4];
  const int t   = threadIdx.x;
  const int sl  = t >> 5;                        // p-slice 0..7
  const int pos = blockIdx.x * 32 + (t & 31);

  const float* base = s_part + pos;
  float a0 = 0.f, a1 = 0.f, a2 = 0.f, a3 = 0.f;
  for (int p = sl; p < NB; p += 32) {            // NB multiple of 32
    a0 += base[(size_t)(p)      * NIDX];
    a1 += base[(size_t)(p + 8)  * NIDX];
    a2 += base[(size_t)(p + 16) * NIDX];
    a3 += base[(size_t)(p + 24) * NIDX];
  }
  red[sl][t & 31] = (a0 + a1) + (a2 + a3);

  if (!UNIFORM) {
    const int c = blockIdx.x >> 4;               // single c per 32-pos block
    float zp = 0.f;
    for (int p = t; p < NB; p += 256) zp += z_part[p * C_ + c];
#pragma unroll
    for (int off = 32; off >= 1; off >>= 1) zp += __shfl_down(zp, off, 64);
    if ((t & 63) == 0) zw[t >> 6] = zp;
  }
  __syncthreads();

  if (t < 32) {
    float acc = 0.f;
#pragma unroll
    for (int s8 = 0; s8 < 8; ++s8) acc += red[s8][t];
    float Z = UNIFORM ? (float)R_ : ((zw[0] + zw[1]) + (zw[2] + zw[3]));
    const int p2 = blockIdx.x * 32 + t;          // co*16 + b
    float s  = acc / Z;
    float sq = s * s;
    float vv = sq * s / ((1.f + sq) * sqrtf(sq));   // exact reference formula
    if (FINAL) out[(p2 & 15) * CO_ + (p2 >> 4)] = vv;
    else       v_buf[p2] = vv;
  }
}

// ---------------------------------------------------------------------------
// FALLBACK (tiny workspace only): 3x W reads, two-stage reduce. Unchanged.
// ---------------------------------------------------------------------------
__global__ __launch_bounds__(256)
void reduce_stageA(const float* __restrict__ s_part, const float* __restrict__ z_part,
                   float* __restrict__ s_mid, float* __restrict__ z_mid, int ppg)
{
  const int idx = blockIdx.x * 256 + threadIdx.x;
  const int g   = blockIdx.y;
  const float* base = s_part + (size_t)g * ppg * NIDX + idx;
  float a0 = 0.f, a1 = 0.f, a2 = 0.f, a3 = 0.f;
  for (int p = 0; p < ppg; p += 4) {
    a0 += base[(size_t)(p + 0) * NIDX];
    a1 += base[(size_t)(p + 1) * NIDX];
    a2 += base[(size_t)(p + 2) * NIDX];
    a3 += base[(size_t)(p + 3) * NIDX];
  }
  s_mid[(size_t)g * NIDX + idx] = (a0 + a1) + (a2 + a3);

  if (blockIdx.x == 0 && threadIdx.x < C_) {
    float z0 = 0.f, z1 = 0.f, z2 = 0.f, z3 = 0.f;
    const float* zb = z_part + (size_t)g * ppg * C_ + threadIdx.x;
    for (int p = 0; p < ppg; p += 4) {
      z0 += zb[(p + 0) * C_];
      z1 += zb[(p + 1) * C_];
      z2 += zb[(p + 2) * C_];
      z3 += zb[(p + 3) * C_];
    }
    z_mid[g * C_ + threadIdx.x] = (z0 + z1) + (z2 + z3);
  }
}

template<int FINAL, int UNIFORM>
__global__ __launch_bounds__(256)
void reduce_squashB(const float* __restrict__ s_mid, const float* __restrict__ z_mid,
                    float* __restrict__ v_buf, float* __restrict__ out)
{
  const int pos = blockIdx.x * 256 + threadIdx.x;
  const int co = pos >> 4, b = pos & 15;
  float acc = 0.f;
#pragma unroll
  for (int g = 0; g < NGRP; ++g) acc += s_mid[(size_t)g * NIDX + pos];
  float Z;
  if (UNIFORM) {
    Z = (float)R_;
  } else {
    const int c = co >> 5;
    float zs = 0.f;
#pragma unroll
    for (int g = 0; g < NGRP; ++g) zs += z_mid[g * C_ + c];
    Z = zs;
  }
  float s  = acc / Z;
  float sq = s * s;
  float vv = sq * s / ((1.f + sq) * sqrtf(sq));
  if (FINAL) out[b * CO_ + co] = vv; else v_buf[pos] = vv;
}

template<int MODE>
__global__ __launch_bounds__(256)
void heavy_pass(const float* __restrict__ x, const float* __restrict__ W,
                const float* __restrict__ v, float* __restrict__ b_buf,
                float* __restrict__ s_part, float* __restrict__ z_part,
                int chunk)
{
  const int t  = threadIdx.x;
  const int co0 = t, co1 = t + 256;
  const int c0 = co0 >> 5, o0 = co0 & 31;
  const int c1 = co1 >> 5;
  const int r0 = blockIdx.x * chunk;

  float sacc0[B_], sacc1[B_];
#pragma unroll
  for (int b = 0; b < B_; ++b) { sacc0[b] = 0.f; sacc1[b] = 0.f; }
  float v0r[B_], v1r[B_];
  if (MODE == 1) {
#pragma unroll
    for (int b = 0; b < B_; ++b) { v0r[b] = v[co0*B_ + b]; v1r[b] = v[co1*B_ + b]; }
  }
  float zacc0 = 0.f, zacc1 = 0.f;

  for (int rr = 0; rr < chunk; ++rr) {
    const int r = r0 + rr;
    const float* Wr = W + (size_t)r * (CO_*IC_);
    const float* xr = x + (size_t)r * IC_;
    float u0[B_], u1[B_];
#pragma unroll
    for (int b = 0; b < B_; ++b) { u0[b] = 0.f; u1[b] = 0.f; }
#pragma unroll
    for (int ic = 0; ic < IC_; ic += 8) {
      float w0c[8], w1c[8];
#pragma unroll
      for (int i = 0; i < 8; i += 4) {
        *(float4*)&w0c[i] = *(const float4*)&Wr[co0*IC_ + ic + i];
        *(float4*)&w1c[i] = *(const float4*)&Wr[co1*IC_ + ic + i];
      }
#pragma unroll
      for (int b = 0; b < B_; ++b) {
        const float* xb = xr + (size_t)b * (R_*IC_) + ic;
#pragma unroll
        for (int i = 0; i < 8; ++i) {
          float xv = xb[i];
          u0[b] = fmaf(w0c[i], xv, u0[b]);
          u1[b] = fmaf(w1c[i], xv, u1[b]);
        }
      }
    }
    float wgt0 = 1.f, wgt1 = 1.f;
    if (MODE == 1) {
      float aa0 = 0.f, aa1 = 0.f;
#pragma unroll
      for (int b = 0; b < B_; ++b) { aa0 = fmaf(u0[b], v0r[b], aa0); aa1 = fmaf(u1[b], v1r[b], aa1); }
#pragma unroll
      for (int off = 16; off >= 1; off >>= 1) { aa0 += __shfl_xor(aa0, off, 32); aa1 += __shfl_xor(aa1, off, 32); }
      float bn0 = b_buf[r*C_ + c0] + aa0 * (1.f/16.f);
      float bn1 = b_buf[r*C_ + c1] + aa1 * (1.f/16.f);
      wgt0 = __expf(bn0); wgt1 = __expf(bn1);
      zacc0 += wgt0; zacc1 += wgt1;
      if (o0 == 0) { b_buf[r*C_ + c0] = bn0; b_buf[r*C_ + c1] = bn1; }
    }
#pragma unroll
    for (int b = 0; b < B_; ++b) { sacc0[b] = fmaf(wgt0, u0[b], sacc0[b]); sacc1[b] = fmaf(wgt1, u1[b], sacc1[b]); }
  }
  float* sp = s_part + (size_t)blockIdx.x * NIDX;
#pragma unroll
  for (int b = 0; b < B_; ++b) { sp[co0*B_ + b] = sacc0[b]; sp[co1*B_ + b] = sacc1[b]; }
  if (MODE == 1 && o0 == 0) { z_part[blockIdx.x*C_ + c0] = zacc0; z_part[blockIdx.x*C_ + c1] = zacc1; }
}

extern "C" void kernel_launch(void* const* d_in, const int* in_sizes, int n_in,
                              void* d_out, int out_size, void* d_ws, size_t ws_size,
                              hipStream_t stream)
{
  const float* x = (const float*)d_in[0];   // [B, R, IC] fp32
  const float* W = (const float*)d_in[1];   // [R, C, OC, IC] fp32 (268 MB)
  float* out = (float*)d_out;               // [B, C, OC, 1] fp32 = 8192 floats

  const size_t uhat_elems = (size_t)R_ * CO_ * B_;       // 33.5M bf16 = 67 MB
  const int nidx_blks = NIDX / 256;                       // 32 (fallback)
  const int NBL_MAX = 512;                                // light-pass blocks

  // Fast path layout: uhat(bf16) | s_part[NB0][8192] | z_part | b_buf | v_buf
  // NB0 = 512 (was 1024): halves pass0's s_part round-trip (R9 single change).
  int NB0 = 512; bool fast = false;
  for (; NB0 >= 64; NB0 >>= 1) {
    size_t need = uhat_elems * 2 +
                  ((size_t)NB0 * NIDX + (size_t)NBL_MAX * C_ + (size_t)R_ * C_ + NIDX) * sizeof(float);
    if (need <= ws_size) { fast = true; break; }
  }

  if (fast) {
    const int NBL    = (NB0 < NBL_MAX) ? NB0 : NBL_MAX;
    const int chunk0 = R_ / NB0;             // 8 at NB0=512
    const int chunkL = R_ / NBL;             // 8 at NBL=512
    ushort* uhat  = (ushort*)d_ws;
    float* s_part = (float*)(uhat + uhat_elems);
    float* z_part = s_part + (size_t)NB0 * NIDX;
    float* b_buf  = z_part + (size_t)NBL_MAX * C_;
    float* v_buf  = b_buf  + (size_t)R_ * C_;

    pass0_mfma<<<NB0, 256, 0, stream>>>(x, W, uhat, s_part, b_buf, chunk0);
    reduce_squash<0,1><<<NIDX/32, 256, 0, stream>>>(s_part, z_part, v_buf, nullptr, NB0);

    light_pass<<<NBL, 512, 0, stream>>>(uhat, v_buf, b_buf, s_part, z_part, chunkL);
    reduce_squash<0,0><<<NIDX/32, 256, 0, stream>>>(s_part, z_part, v_buf, nullptr, NBL);

    light_pass<<<NBL, 512, 0, stream>>>(uhat, v_buf, b_buf, s_part, z_part, chunkL);
    reduce_squash<1,0><<<NIDX/32, 256, 0, stream>>>(s_part, z_part, nullptr, out, NBL);
    return;
  }

  // ---------------- Fallback: heavy path (tiny ws) ----------------
  int NB = 512;
  while (NB > 64) {
    size_t need = ((size_t)NB * NIDX + (size_t)NB * C_ + (size_t)R_ * C_ + NIDX +
                   (size_t)NGRP * NIDX + NGRP * C_) * sizeof(float);
    if (need <= ws_size) break;
    NB >>= 1;
  }
  const int chunk = R_ / NB;
  const int ppg   = NB / NGRP;
  float* s_part = (float*)d_ws;
  float* z_part = s_part + (size_t)NB * NIDX;
  float* b_buf  = z_part + (size_t)NB * C_;
  float* v_buf  = b_buf  + (size_t)R_ * C_;
  float* s_mid  = v_buf  + NIDX;
  float* z_mid  = s_mid  + (size_t)NGRP * NIDX;

  (void)hipMemsetAsync(b_buf, 0, (size_t)R_ * C_ * sizeof(float), stream);
  heavy_pass<0><<<NB, 256, 0, stream>>>(x, W, nullptr, b_buf, s_part, z_part, chunk);
  reduce_stageA<<<dim3(nidx_blks, NGRP), 256, 0, stream>>>(s_part, z_part, s_mid, z_mid, ppg);
  reduce_squashB<0,1><<<nidx_blks, 256, 0, stream>>>(s_mid, z_mid, v_buf, nullptr);
  heavy_pass<1><<<NB, 256, 0, stream>>>(x, W, v_buf, b_buf, s_part, z_part, chunk);
  reduce_stageA<<<dim3(nidx_blks, NGRP), 256, 0, stream>>>(s_part, z_part, s_mid, z_mid, ppg);
  reduce_squashB<0,0><<<nidx_blks, 256, 0, stream>>>(s_mid, z_mid, v_buf, nullptr);
  heavy_pass<1><<<NB, 256, 0, stream>>>(x, W, v_buf, b_buf, s_part, z_part, chunk);
  reduce_stageA<<<dim3(nidx_blks, NGRP), 256, 0, stream>>>(s_part, z_part, s_mid, z_mid, ppg);
  reduce_squashB<1,0><<<nidx_blks, 256, 0, stream>>>(s_mid, z_mid, nullptr, out);
}

// Round 10
// 138.499 us; speedup vs baseline: 3.0467x; 1.0012x over previous
//
#include <hip/hip_runtime.h>
#include <math.h>

// Shapes (fixed by the reference)
#define B_  16
#define R_  4096
#define C_  16
#define OC_ 32
#define IC_ 32
#define CO_ 512   // C_*OC_
#define NIDX (B_*CO_)       // 8192 output elements
#define NGRP 16             // fallback stage-A p-groups

typedef unsigned int uint;
typedef unsigned short ushort;

typedef __attribute__((ext_vector_type(8))) short bf16x8;   // 8 bf16 = 4 VGPR
typedef __attribute__((ext_vector_type(4))) float f32x4;    // MFMA acc

__device__ __forceinline__ ushort f2bf(float f) {           // RNE float->bf16
  uint u = __float_as_uint(f);
  return (ushort)((u + 0x7FFFu + ((u >> 16) & 1u)) >> 16);
}
__device__ __forceinline__ float bf2f(ushort h) {
  return __uint_as_float(((uint)h) << 16);
}

// ---------------------------------------------------------------------------
// Pass 0 (MFMA): read W once (plain cached loads — nt regressed, R7/R8),
// u_hat bf16 [r][co][b] + uniform-sum partials s_part [blk][co][b].
// R10 single change vs R9: CHUNK is a template parameter and the rr loop is
// unrolled x2 so W loads for rr+1 issue under rr's convert/MFMA/store tail
// (pass0 diagnosed load-issue-limited at ~3.5 TB/s, not BW-saturated).
// Frag maps (m89/m97-verified): A row=lane&15 (=b), k=(lane>>4)*8+j contiguous;
// B col=lane&15 (=co), k contiguous; C/D col=lane&15 (=co), row b=(lane>>4)*4+reg.
// ---------------------------------------------------------------------------
template<int CHUNK>
__global__ __launch_bounds__(256)
void pass0_mfma(const float* __restrict__ x, const float* __restrict__ W,
                ushort* __restrict__ uhat, float* __restrict__ s_part,
                float* __restrict__ b_buf)
{
  const int wid  = threadIdx.x >> 6;      // 0..3
  const int lane = threadIdx.x & 63;
  const int col  = lane & 15;             // = b for A, = co-offset for B/C
  const int krow = lane >> 4;             // 0..3
  const int r0   = blockIdx.x * CHUNK;

  // zero routing logits for this block's routes (replaces memset dispatch)
  for (int i = threadIdx.x; i < CHUNK * C_; i += 256) b_buf[r0 * C_ + i] = 0.f;

  f32x4 sacc[8];
#pragma unroll
  for (int j = 0; j < 8; ++j) sacc[j] = (f32x4){0.f, 0.f, 0.f, 0.f};

#pragma unroll 2
  for (int rr = 0; rr < CHUNK; ++rr) {
    const int r = r0 + rr;
    // A-frag: x[b=col][r][krow*8 .. +8] fp32 -> bf16 in-reg (L2-hot)
    const float* xp = x + ((size_t)col * R_ + r) * IC_ + krow * 8;
    float4 x0 = *(const float4*)xp;
    float4 x1 = *(const float4*)(xp + 4);
    bf16x8 af;
    af[0] = (short)f2bf(x0.x); af[1] = (short)f2bf(x0.y);
    af[2] = (short)f2bf(x0.z); af[3] = (short)f2bf(x0.w);
    af[4] = (short)f2bf(x1.x); af[5] = (short)f2bf(x1.y);
    af[6] = (short)f2bf(x1.z); af[7] = (short)f2bf(x1.w);

#pragma unroll
    for (int j = 0; j < 8; ++j) {
      const int co = (wid * 8 + j) * 16 + col;
      const float* wp = W + ((size_t)r * CO_ + co) * IC_ + krow * 8;
      float4 w0 = *(const float4*)(wp);
      float4 w1 = *(const float4*)(wp + 4);
      bf16x8 bf;
      bf[0] = (short)f2bf(w0.x); bf[1] = (short)f2bf(w0.y);
      bf[2] = (short)f2bf(w0.z); bf[3] = (short)f2bf(w0.w);
      bf[4] = (short)f2bf(w1.x); bf[5] = (short)f2bf(w1.y);
      bf[6] = (short)f2bf(w1.z); bf[7] = (short)f2bf(w1.w);

      f32x4 d = __builtin_amdgcn_mfma_f32_16x16x32_bf16(
          af, bf, (f32x4){0.f, 0.f, 0.f, 0.f}, 0, 0, 0);
      sacc[j] += d;

      // u_hat[r][co][b]: lane writes b = krow*4 .. +4 (8B, coalesced), cached
      union { ushort us[4]; uint2 q; } pk;
      pk.us[0] = f2bf(d[0]); pk.us[1] = f2bf(d[1]);
      pk.us[2] = f2bf(d[2]); pk.us[3] = f2bf(d[3]);
      *(uint2*)(uhat + ((size_t)r * CO_ + co) * B_ + krow * 4) = pk.q;
    }
  }

  // s_part layout [blk][co*B_ + b]: lane owns co, b = krow*4..+4 -> 16B store
  float* sp = s_part + (size_t)blockIdx.x * NIDX;
#pragma unroll
  for (int j = 0; j < 8; ++j) {
    const int co = (wid * 8 + j) * 16 + col;
    *(f32x4*)(sp + co * B_ + krow * 4) = sacc[j];
  }
}

// ---------------------------------------------------------------------------
// Light pass: fused agreement(it) + weighted-sum(it+1), streaming u_hat (bf16,
// plain cached loads — LLC-resident). v and s_part in [co][b] layout.
// ---------------------------------------------------------------------------
__global__ __launch_bounds__(512)
void light_pass(const ushort* __restrict__ uhat, const float* __restrict__ v,
                float* __restrict__ b_buf, float* __restrict__ s_part,
                float* __restrict__ z_part, int chunk)
{
  const int t = threadIdx.x;                 // co = t
  const int c = t >> 5, o = t & 31;
  const int r0 = blockIdx.x * chunk;

  float vr[B_], sacc[B_];
#pragma unroll
  for (int k = 0; k < 4; ++k) *(float4*)&vr[4 * k] = *(const float4*)(v + t * B_ + 4 * k);
#pragma unroll
  for (int b = 0; b < B_; ++b) sacc[b] = 0.f;
  float zacc = 0.f;

#pragma unroll 2
  for (int rr = 0; rr < chunk; ++rr) {
    const int r = r0 + rr;
    const uint4* up = (const uint4*)(uhat + ((size_t)r * CO_ + t) * B_);
    union { ushort us[16]; uint4 q[2]; } pk;
    pk.q[0] = up[0]; pk.q[1] = up[1];
    float u[B_]; float aa = 0.f;
#pragma unroll
    for (int b = 0; b < B_; ++b) { u[b] = bf2f(pk.us[b]); aa = fmaf(u[b], vr[b], aa); }
#pragma unroll
    for (int off = 16; off >= 1; off >>= 1) aa += __shfl_xor(aa, off, 32);
    float bn = b_buf[r * C_ + c] + aa * (1.f / 16.f);
    float w  = __expf(bn);
    zacc += w;
    if (o == 0) b_buf[r * C_ + c] = bn;
#pragma unroll
    for (int b = 0; b < B_; ++b) sacc[b] = fmaf(w, u[b], sacc[b]);
  }
  float* sp = s_part + (size_t)blockIdx.x * NIDX;
#pragma unroll
  for (int k = 0; k < 4; ++k) *(float4*)(sp + t * B_ + 4 * k) = *(float4*)&sacc[4 * k];
  if (o == 0) z_part[blockIdx.x * C_ + c] = zacc;
}

// ---------------------------------------------------------------------------
// Fused final reduce + normalize + squash.
// Grid 256 blocks x 256 threads: block handles 32 consecutive pos, 8 p-slices.
// ---------------------------------------------------------------------------
template<int FINAL, int UNIFORM>
__global__ __launch_bounds__(256)
void reduce_squash(const float* __restrict__ s_part, const float* __restrict__ z_part,
                   float* __restrict__ v_buf, float* __restrict__ out, int NB)
{
  __shared__ float red[8][32];
  __shared__ float zw[4];
  const int t   = threadIdx.x;
  const int sl  = t >> 5;                        // p-slice 0..7
  const int pos = blockIdx.x * 32 + (t & 31);

  const float* base = s_part + pos;
  float a0 = 0.f, a1 = 0.f, a2 = 0.f, a3 = 0.f;
  for (int p = sl; p < NB; p += 32) {            // NB multiple of 32
    a0 += base[(size_t)(p)      * NIDX];
    a1 += base[(size_t)(p + 8)  * NIDX];
    a2 += base[(size_t)(p + 16) * NIDX];
    a3 += base[(size_t)(p + 24) * NIDX];
  }
  red[sl][t & 31] = (a0 + a1) + (a2 + a3);

  if (!UNIFORM) {
    const int c = blockIdx.x >> 4;               // single c per 32-pos block
    float zp = 0.f;
    for (int p = t; p < NB; p += 256) zp += z_part[p * C_ + c];
#pragma unroll
    for (int off = 32; off >= 1; off >>= 1) zp += __shfl_down(zp, off, 64);
    if ((t & 63) == 0) zw[t >> 6] = zp;
  }
  __syncthreads();

  if (t < 32) {
    float acc = 0.f;
#pragma unroll
    for (int s8 = 0; s8 < 8; ++s8) acc += red[s8][t];
    float Z = UNIFORM ? (float)R_ : ((zw[0] + zw[1]) + (zw[2] + zw[3]));
    const int p2 = blockIdx.x * 32 + t;          // co*16 + b
    float s  = acc / Z;
    float sq = s * s;
    float vv = sq * s / ((1.f + sq) * sqrtf(sq));   // exact reference formula
    if (FINAL) out[(p2 & 15) * CO_ + (p2 >> 4)] = vv;
    else       v_buf[p2] = vv;
  }
}

// ---------------------------------------------------------------------------
// FALLBACK (tiny workspace only): 3x W reads, two-stage reduce. Unchanged.
// ---------------------------------------------------------------------------
__global__ __launch_bounds__(256)
void reduce_stageA(const float* __restrict__ s_part, const float* __restrict__ z_part,
                   float* __restrict__ s_mid, float* __restrict__ z_mid, int ppg)
{
  const int idx = blockIdx.x * 256 + threadIdx.x;
  const int g   = blockIdx.y;
  const float* base = s_part + (size_t)g * ppg * NIDX + idx;
  float a0 = 0.f, a1 = 0.f, a2 = 0.f, a3 = 0.f;
  for (int p = 0; p < ppg; p += 4) {
    a0 += base[(size_t)(p + 0) * NIDX];
    a1 += base[(size_t)(p + 1) * NIDX];
    a2 += base[(size_t)(p + 2) * NIDX];
    a3 += base[(size_t)(p + 3) * NIDX];
  }
  s_mid[(size_t)g * NIDX + idx] = (a0 + a1) + (a2 + a3);

  if (blockIdx.x == 0 && threadIdx.x < C_) {
    float z0 = 0.f, z1 = 0.f, z2 = 0.f, z3 = 0.f;
    const float* zb = z_part + (size_t)g * ppg * C_ + threadIdx.x;
    for (int p = 0; p < ppg; p += 4) {
      z0 += zb[(p + 0) * C_];
      z1 += zb[(p + 1) * C_];
      z2 += zb[(p + 2) * C_];
      z3 += zb[(p + 3) * C_];
    }
    z_mid[g * C_ + threadIdx.x] = (z0 + z1) + (z2 + z3);
  }
}

template<int FINAL, int UNIFORM>
__global__ __launch_bounds__(256)
void reduce_squashB(const float* __restrict__ s_mid, const float* __restrict__ z_mid,
                    float* __restrict__ v_buf, float* __restrict__ out)
{
  const int pos = blockIdx.x * 256 + threadIdx.x;
  const int co = pos >> 4, b = pos & 15;
  float acc = 0.f;
#pragma unroll
  for (int g = 0; g < NGRP; ++g) acc += s_mid[(size_t)g * NIDX + pos];
  float Z;
  if (UNIFORM) {
    Z = (float)R_;
  } else {
    const int c = co >> 5;
    float zs = 0.f;
#pragma unroll
    for (int g = 0; g < NGRP; ++g) zs += z_mid[g * C_ + c];
    Z = zs;
  }
  float s  = acc / Z;
  float sq = s * s;
  float vv = sq * s / ((1.f + sq) * sqrtf(sq));
  if (FINAL) out[b * CO_ + co] = vv; else v_buf[pos] = vv;
}

template<int MODE>
__global__ __launch_bounds__(256)
void heavy_pass(const float* __restrict__ x, const float* __restrict__ W,
                const float* __restrict__ v, float* __restrict__ b_buf,
                float* __restrict__ s_part, float* __restrict__ z_part,
                int chunk)
{
  const int t  = threadIdx.x;
  const int co0 = t, co1 = t + 256;
  const int c0 = co0 >> 5, o0 = co0 & 31;
  const int c1 = co1 >> 5;
  const int r0 = blockIdx.x * chunk;

  float sacc0[B_], sacc1[B_];
#pragma unroll
  for (int b = 0; b < B_; ++b) { sacc0[b] = 0.f; sacc1[b] = 0.f; }
  float v0r[B_], v1r[B_];
  if (MODE == 1) {
#pragma unroll
    for (int b = 0; b < B_; ++b) { v0r[b] = v[co0*B_ + b]; v1r[b] = v[co1*B_ + b]; }
  }
  float zacc0 = 0.f, zacc1 = 0.f;

  for (int rr = 0; rr < chunk; ++rr) {
    const int r = r0 + rr;
    const float* Wr = W + (size_t)r * (CO_*IC_);
    const float* xr = x + (size_t)r * IC_;
    float u0[B_], u1[B_];
#pragma unroll
    for (int b = 0; b < B_; ++b) { u0[b] = 0.f; u1[b] = 0.f; }
#pragma unroll
    for (int ic = 0; ic < IC_; ic += 8) {
      float w0c[8], w1c[8];
#pragma unroll
      for (int i = 0; i < 8; i += 4) {
        *(float4*)&w0c[i] = *(const float4*)&Wr[co0*IC_ + ic + i];
        *(float4*)&w1c[i] = *(const float4*)&Wr[co1*IC_ + ic + i];
      }
#pragma unroll
      for (int b = 0; b < B_; ++b) {
        const float* xb = xr + (size_t)b * (R_*IC_) + ic;
#pragma unroll
        for (int i = 0; i < 8; ++i) {
          float xv = xb[i];
          u0[b] = fmaf(w0c[i], xv, u0[b]);
          u1[b] = fmaf(w1c[i], xv, u1[b]);
        }
      }
    }
    float wgt0 = 1.f, wgt1 = 1.f;
    if (MODE == 1) {
      float aa0 = 0.f, aa1 = 0.f;
#pragma unroll
      for (int b = 0; b < B_; ++b) { aa0 = fmaf(u0[b], v0r[b], aa0); aa1 = fmaf(u1[b], v1r[b], aa1); }
#pragma unroll
      for (int off = 16; off >= 1; off >>= 1) { aa0 += __shfl_xor(aa0, off, 32); aa1 += __shfl_xor(aa1, off, 32); }
      float bn0 = b_buf[r*C_ + c0] + aa0 * (1.f/16.f);
      float bn1 = b_buf[r*C_ + c1] + aa1 * (1.f/16.f);
      wgt0 = __expf(bn0); wgt1 = __expf(bn1);
      zacc0 += wgt0; zacc1 += wgt1;
      if (o0 == 0) { b_buf[r*C_ + c0] = bn0; b_buf[r*C_ + c1] = bn1; }
    }
#pragma unroll
    for (int b = 0; b < B_; ++b) { sacc0[b] = fmaf(wgt0, u0[b], sacc0[b]); sacc1[b] = fmaf(wgt1, u1[b], sacc1[b]); }
  }
  float* sp = s_part + (size_t)blockIdx.x * NIDX;
#pragma unroll
  for (int b = 0; b < B_; ++b) { sp[co0*B_ + b] = sacc0[b]; sp[co1*B_ + b] = sacc1[b]; }
  if (MODE == 1 && o0 == 0) { z_part[blockIdx.x*C_ + c0] = zacc0; z_part[blockIdx.x*C_ + c1] = zacc1; }
}

extern "C" void kernel_launch(void* const* d_in, const int* in_sizes, int n_in,
                              void* d_out, int out_size, void* d_ws, size_t ws_size,
                              hipStream_t stream)
{
  const float* x = (const float*)d_in[0];   // [B, R, IC] fp32
  const float* W = (const float*)d_in[1];   // [R, C, OC, IC] fp32 (268 MB)
  float* out = (float*)d_out;               // [B, C, OC, 1] fp32 = 8192 floats

  const size_t uhat_elems = (size_t)R_ * CO_ * B_;       // 33.5M bf16 = 67 MB
  const int nidx_blks = NIDX / 256;                       // 32 (fallback)
  const int NBL_MAX = 512;                                // light-pass blocks

  // Fast path layout: uhat(bf16) | s_part[NB0][8192] | z_part | b_buf | v_buf
  int NB0 = 512; bool fast = false;
  for (; NB0 >= 256; NB0 >>= 1) {
    size_t need = uhat_elems * 2 +
                  ((size_t)NB0 * NIDX + (size_t)NBL_MAX * C_ + (size_t)R_ * C_ + NIDX) * sizeof(float);
    if (need <= ws_size) { fast = true; break; }
  }

  if (fast) {
    const int NBL    = (NB0 < NBL_MAX) ? NB0 : NBL_MAX;
    const int chunkL = R_ / NBL;             // 8 at NBL=512
    ushort* uhat  = (ushort*)d_ws;
    float* s_part = (float*)(uhat + uhat_elems);
    float* z_part = s_part + (size_t)NB0 * NIDX;
    float* b_buf  = z_part + (size_t)NBL_MAX * C_;
    float* v_buf  = b_buf  + (size_t)R_ * C_;

    if (NB0 == 512)
      pass0_mfma<8><<<512, 256, 0, stream>>>(x, W, uhat, s_part, b_buf);
    else
      pass0_mfma<16><<<256, 256, 0, stream>>>(x, W, uhat, s_part, b_buf);
    reduce_squash<0,1><<<NIDX/32, 256, 0, stream>>>(s_part, z_part, v_buf, nullptr, NB0);

    light_pass<<<NBL, 512, 0, stream>>>(uhat, v_buf, b_buf, s_part, z_part, chunkL);
    reduce_squash<0,0><<<NIDX/32, 256, 0, stream>>>(s_part, z_part, v_buf, nullptr, NBL);

    light_pass<<<NBL, 512, 0, stream>>>(uhat, v_buf, b_buf, s_part, z_part, chunkL);
    reduce_squash<1,0><<<NIDX/32, 256, 0, stream>>>(s_part, z_part, nullptr, out, NBL);
    return;
  }

  // ---------------- Fallback: heavy path (tiny ws) ----------------
  int NB = 512;
  while (NB > 64) {
    size_t need = ((size_t)NB * NIDX + (size_t)NB * C_ + (size_t)R_ * C_ + NIDX +
                   (size_t)NGRP * NIDX + NGRP * C_) * sizeof(float);
    if (need <= ws_size) break;
    NB >>= 1;
  }
  const int chunk = R_ / NB;
  const int ppg   = NB / NGRP;
  float* s_part = (float*)d_ws;
  float* z_part = s_part + (size_t)NB * NIDX;
  float* b_buf  = z_part + (size_t)NB * C_;
  float* v_buf  = b_buf  + (size_t)R_ * C_;
  float* s_mid  = v_buf  + NIDX;
  float* z_mid  = s_mid  + (size_t)NGRP * NIDX;

  (void)hipMemsetAsync(b_buf, 0, (size_t)R_ * C_ * sizeof(float), stream);
  heavy_pass<0><<<NB, 256, 0, stream>>>(x, W, nullptr, b_buf, s_part, z_part, chunk);
  reduce_stageA<<<dim3(nidx_blks, NGRP), 256, 0, stream>>>(s_part, z_part, s_mid, z_mid, ppg);
  reduce_squashB<0,1><<<nidx_blks, 256, 0, stream>>>(s_mid, z_mid, v_buf, nullptr);
  heavy_pass<1><<<NB, 256, 0, stream>>>(x, W, v_buf, b_buf, s_part, z_part, chunk);
  reduce_stageA<<<dim3(nidx_blks, NGRP), 256, 0, stream>>>(s_part, z_part, s_mid, z_mid, ppg);
  reduce_squashB<0,0><<<nidx_blks, 256, 0, stream>>>(s_mid, z_mid, v_buf, nullptr);
  heavy_pass<1><<<NB, 256, 0, stream>>>(x, W, v_buf, b_buf, s_part, z_part, chunk);
  reduce_stageA<<<dim3(nidx_blks, NGRP), 256, 0, stream>>>(s_part, z_part, s_mid, z_mid, ppg);
  reduce_squashB<1,0><<<nidx_blks, 256, 0, stream>>>(s_mid, z_mid, nullptr, out);
}